// Round 4
// baseline (3098.424 us; speedup 1.0000x reference)
//
#include <hip/hip_runtime.h>
#include <math.h>

#define AA 256
#define EE 256
#define CC (AA + EE + AA*EE)   // 66048
#define TT 1024
#define VV 1024
#define NSTRIP 16
#define SH 64
#define LSTEPS 1087            // local steps per strip: 1023 + 64
#define NEGBIG (-3.0e38f)      // finite stand-in for -inf (ref has -inf at empty bins)

__device__ __forceinline__ float lae(float x, float y) {
    float m = fmaxf(x, y);
    if (m == -INFINITY) return -INFINITY;
    return m + log1pf(__expf(-fabsf(x - y)));
}

// order-preserving float->uint key for atomicMax
__device__ __forceinline__ unsigned fkey(float f) {
    unsigned u = __float_as_uint(f);
    return (u & 0x80000000u) ? ~u : (u | 0x80000000u);
}
__device__ __forceinline__ float fdec(unsigned k) {
    return __uint_as_float((k & 0x80000000u) ? (k & 0x7FFFFFFFu) : ~k);
}
#define KEY_NEGINF 0x007FFFFFu   // fkey(-inf)

__device__ __forceinline__ float safe_out(float v) {
    if (!(v > NEGBIG)) return NEGBIG;   // catches -inf, NaN
    return v;
}

// ---------------- init bins + pipeline flags ----------------
__global__ void k_initbins(unsigned* __restrict__ mkey, float* __restrict__ sbuf,
                           unsigned* __restrict__ flags) {
    int i = blockIdx.x * 256 + threadIdx.x;
    if (i < CC) { mkey[i] = 0u; sbuf[i] = 0.0f; }
    if (i < 32 * NSTRIP) flags[i] = 0u;
}

// ---------------- prep: wd, wi, row0 (prefix), rowlast (suffix) ----------------
__global__ __launch_bounds__(1024)
void k_prep(const float* __restrict__ W, const int* __restrict__ ar, const int* __restrict__ en,
            float* __restrict__ wd, float* __restrict__ wi,
            float* __restrict__ row0, float* __restrict__ rowlast) {
    __shared__ float pre[VV];
    __shared__ float suf[VV];
    int j = threadIdx.x;
    float wi_j = W[AA + en[j]];
    wi[j] = wi_j;
    wd[j] = W[ar[j]];
    float x = (j >= 1) ? wi_j : 0.0f;
    pre[j] = x;
    suf[j] = x;
    __syncthreads();
    for (int off = 1; off < VV; off <<= 1) {
        float addp = (j >= off) ? pre[j - off] : 0.0f;
        float adds = (j + off < VV) ? suf[j + off] : 0.0f;
        __syncthreads();
        pre[j] += addp;
        suf[j] += adds;
        __syncthreads();
    }
    row0[j] = pre[j];                               // row0[j] = sum wi[1..j], row0[0]=0
    rowlast[j] = (j == VV - 1) ? 0.0f : suf[j + 1]; // rowlast[j] = sum wi[j+1..V-1]
}

// ---------------- substitution weights in strip-step layout ----------------
// wss[dirb][d][r]: dirb = dir*16+b; cell (rr=64b+r, jk=d-r) in DP coords.
// dir 0 (fwd, alpha): ws = W[A+E+256*ar[rr]+en[jk]]
// dir 1 (bwd, beta mirrored): ws = W[A+E+256*ar[1024-rr]+en[1024-jk]]
__global__ __launch_bounds__(64)
void k_wsstrip(const float* __restrict__ W, const int* __restrict__ ar, const int* __restrict__ en,
               float* __restrict__ wss) {
    int d = blockIdx.x;          // 0..1086
    int dirb = blockIdx.y;       // 0..31
    int dir = dirb >> 4, b = dirb & 15;
    int r = threadIdx.x;
    int rr = (b << 6) + r;
    int jk = d - r;
    float v = 0.0f;
    if (rr >= 1 && jk >= 1 && jk < 1024) {
        v = (dir == 0) ? W[AA + EE + (ar[rr] << 8) + en[jk]]
                       : W[AA + EE + (ar[1024 - rr] << 8) + en[1024 - jk]];
    }
    wss[((size_t)dirb * LSTEPS + d) * SH + r] = v;
}

// ---------------- pipelined strip DP: 32 blocks x 1 wave, no barriers ----------------
// Blocks 0..15: forward strips (alpha); 16..31: backward strips (beta, mirrored coords).
// Lane r = row rr = 64b + r. Step d: column jk = d - r. Intra-strip dep via shfl_up;
// inter-strip dep via boundary buffer + agent-scope flag handshake (64-col chunks).
__global__ __launch_bounds__(64)
void k_dp_strip(const float* __restrict__ wss, const float* __restrict__ wd,
                const float* __restrict__ wi, const float* __restrict__ row0,
                const float* __restrict__ rowlast,
                float* __restrict__ a_sd, float* __restrict__ bnd,
                unsigned* __restrict__ flags) {
    __shared__ float wi_s[1024];
    __shared__ float seed_s[1024];
    const int tid = threadIdx.x;
    const int dirb = blockIdx.x;        // 0..31
    const int dir = dirb >> 4;
    const int b = dirb & 15;
    const bool fwd = (dir == 0);
    const int rr = (b << 6) + tid;

    for (int x = tid; x < 1024; x += 64) {
        wi_s[x] = (x >= 1) ? (fwd ? wi[x] : wi[1024 - x]) : 0.0f;
        if (b == 0) seed_s[x] = fwd ? row0[x] : rowlast[1023 - x];
    }
    const float mywd = (rr >= 1) ? (fwd ? wd[rr] : wd[1024 - rr]) : 0.0f;
    const bool is_seed = (b == 0) && (tid == 0);

    const size_t sbase = (size_t)dirb * LSTEPS * SH + tid;
    const float* __restrict__ wme = wss + sbase;
    float* __restrict__ ame = a_sd + sbase;
    float* __restrict__ bnd_me = bnd + (size_t)dirb * 1024;
    const float* __restrict__ bnd_prev = bnd + (size_t)(dirb - 1) * 1024;

    float vm1 = -INFINITY, upprev = -INFINITY, bprev = -INFINITY, bvals = -INFINITY;
    // 4-deep ws prefetch pipeline
    float w0 = wme[0 * SH], w1 = wme[1 * SH], w2 = wme[2 * SH], w3 = wme[3 * SH];

    for (int d = 0; d < LSTEPS; ++d) {
        // consumer: fetch next 64-col boundary chunk (lane0 of strips b>0)
        if ((d & 63) == 0 && d < 1024 && b > 0) {
            unsigned fidx = (unsigned)(dirb - 1) * NSTRIP + (unsigned)(d >> 6);
            while (__hip_atomic_load(&flags[fidx], __ATOMIC_ACQUIRE,
                                     __HIP_MEMORY_SCOPE_AGENT) == 0u) {
                __builtin_amdgcn_s_sleep(1);
            }
            bvals = __hip_atomic_load(&bnd_prev[d + tid], __ATOMIC_RELAXED,
                                      __HIP_MEMORY_SCOPE_AGENT);
        }
        float up1 = __shfl_up(vm1, 1);
        float up2 = upprev;
        float bc = __shfl(bvals, d & 63);
        if (tid == 0) { up1 = bc; up2 = bprev; bprev = bc; }

        int jk = d - tid;
        float wsv = w0; w0 = w1; w1 = w2; w2 = w3;
        w3 = (d + 4 < LSTEPS) ? wme[(size_t)(d + 4) * SH] : 0.0f;

        float v;
        if (is_seed) {
            v = (d < 1024) ? seed_s[d] : -INFINITY;
        } else if ((unsigned)jk < 1024u) {
            float del = mywd + up1;
            if (jk >= 1) {
                float c = lae(del, wsv + up2);
                v = lae(c, vm1 + wi_s[jk]);
            } else v = del;
        } else v = -INFINITY;

        ame[(size_t)d * SH] = v;
        upprev = up1;
        vm1 = v;

        // producer: lane 63 publishes boundary row in 64-col chunks
        if (tid == 63 && (unsigned)jk < 1024u) {
            __hip_atomic_store(&bnd_me[jk], v, __ATOMIC_RELAXED, __HIP_MEMORY_SCOPE_AGENT);
            if ((jk & 63) == 63 && b < NSTRIP - 1) {
                __hip_atomic_store(&flags[(unsigned)dirb * NSTRIP + (unsigned)(jk >> 6)], 1u,
                                   __ATOMIC_RELEASE, __HIP_MEMORY_SCOPE_AGENT);
            }
        }
    }
}

// ---------------- strip-step layout -> row-major ----------------
// value at a_sd[dirb][d][r] is cell (rr=64b+r, jk=d-r):
//   dir 0: alpha[rr][jk]     dir 1: beta[1023-rr][1023-jk]
__global__ __launch_bounds__(256)
void k_striptr(const float* __restrict__ a_sd, float* __restrict__ outm, int dir) {
    __shared__ float tile[127 * 65];
    int j0 = blockIdx.x * 64;            // jk tile base
    int b  = blockIdx.y;                 // strip
    const float* __restrict__ src = a_sd + (size_t)(dir * NSTRIP + b) * LSTEPS * SH;
    int lane = threadIdx.x & 63;
    int grp  = threadIdx.x >> 6;         // 0..3
    for (int p = 0; p < 32; ++p) {
        int dl = (p << 2) + grp;         // 0..127
        if (dl < 127) {
            int d = j0 + dl;             // <= 960+126 = 1086
            tile[dl * 65 + lane] = src[(size_t)d * SH + lane];
        }
    }
    __syncthreads();
    for (int p = 0; p < 16; ++p) {
        int r = (p << 2) + grp;
        int jl = lane;
        float v = tile[(r + jl) * 65 + r];
        int rr = (b << 6) + r;
        int jk = j0 + jl;
        int t = dir ? (1023 - rr) : rr;
        int j = dir ? (1023 - jk) : jk;
        outm[(size_t)t * 1024 + j] = v;
    }
}

// ---------------- block reduce helpers (256 threads = 4 waves) ----------------
__device__ __forceinline__ float blk_max(float v, float* sm) {
    for (int off = 32; off > 0; off >>= 1) v = fmaxf(v, __shfl_xor(v, off));
    if ((threadIdx.x & 63) == 0) sm[threadIdx.x >> 6] = v;
    __syncthreads();
    float r = fmaxf(fmaxf(sm[0], sm[1]), fmaxf(sm[2], sm[3]));
    __syncthreads();
    return r;
}
__device__ __forceinline__ float blk_sum(float v, float* sm) {
    for (int off = 32; off > 0; off >>= 1) v += __shfl_xor(v, off);
    if ((threadIdx.x & 63) == 0) sm[threadIdx.x >> 6] = v;
    __syncthreads();
    float r = sm[0] + sm[1] + sm[2] + sm[3];
    __syncthreads();
    return r;
}

// ---------------- delete row reduction: rowred[t] = LSE_j(alpha[t-1][j]+beta[t][j]) ----------------
__global__ void k_rowred(const float* __restrict__ alpha, const float* __restrict__ beta,
                         float* __restrict__ rowred) {
    __shared__ float sm[4];
    int t = 1 + blockIdx.x;
    int tid = threadIdx.x;
    float v[4]; float m = -INFINITY;
    for (int i = 0; i < 4; ++i) {
        int j = tid + (i << 8);
        v[i] = alpha[(size_t)(t - 1) * VV + j] + beta[(size_t)t * VV + j];
        m = fmaxf(m, v[i]);
    }
    m = blk_max(m, sm);
    float s = 0.0f;
    for (int i = 0; i < 4; ++i) s += __expf(v[i] - m);
    s = blk_sum(s, sm);
    if (tid == 0) rowred[t] = m + logf(s);
}

// ---------------- insert col reduction: colred[j] = LSE_t(alpha[t][j-1]+beta[t][j]) ----------------
__global__ void k_colred(const float* __restrict__ alpha, const float* __restrict__ beta,
                         float* __restrict__ colred) {
    __shared__ float sm[4];
    int j = 1 + blockIdx.x;
    int tid = threadIdx.x;
    float v[4]; float m = -INFINITY;
    for (int i = 0; i < 4; ++i) {
        int t = tid + (i << 8);
        v[i] = alpha[(size_t)t * VV + (j - 1)] + beta[(size_t)t * VV + j];
        m = fmaxf(m, v[i]);
    }
    m = blk_max(m, sm);
    float s = 0.0f;
    for (int i = 0; i < 4; ++i) s += __expf(v[i] - m);
    s = blk_sum(s, sm);
    if (tid == 0) colred[j] = m + logf(s);
}

// ---------------- substitution bins: two-pass atomic LSE over (a,e) ----------------
__global__ void k_smax(const float* __restrict__ alpha, const float* __restrict__ beta,
                       const int* __restrict__ ar, const int* __restrict__ en,
                       unsigned* __restrict__ mkey) {
    int t = 1 + blockIdx.x;
    int base = AA + EE + (ar[t] << 8);
    for (int j = 1 + threadIdx.x; j <= VV - 1; j += 256) {
        float v = alpha[(size_t)(t - 1) * VV + (j - 1)] + beta[(size_t)t * VV + j];
        atomicMax(&mkey[base + en[j]], fkey(v));
    }
}
__global__ void k_ssum(const float* __restrict__ alpha, const float* __restrict__ beta,
                       const int* __restrict__ ar, const int* __restrict__ en,
                       const unsigned* __restrict__ mkey, float* __restrict__ sbuf) {
    int t = 1 + blockIdx.x;
    int base = AA + EE + (ar[t] << 8);
    for (int j = 1 + threadIdx.x; j <= VV - 1; j += 256) {
        float v = alpha[(size_t)(t - 1) * VV + (j - 1)] + beta[(size_t)t * VV + j];
        int b = base + en[j];
        atomicAdd(&sbuf[b], __expf(v - fdec(mkey[b])));
    }
}
__global__ void k_sfin(const unsigned* __restrict__ mkey, const float* __restrict__ sbuf,
                       const float* __restrict__ W, float* __restrict__ out) {
    int k = blockIdx.x * 256 + threadIdx.x;     // 0..65535
    int id = AA + EE + k;
    unsigned key = mkey[id];
    float v = (key > KEY_NEGINF) ? (W[id] + fdec(key) + logf(sbuf[id])) : NEGBIG;
    out[id] = safe_out(v);
}

// ---------------- delete / insert final binning ----------------
__global__ void k_dbins(const int* __restrict__ ar, const float* __restrict__ rowred,
                        const float* __restrict__ W, float* __restrict__ out) {
    int a = threadIdx.x;
    float m = -INFINITY, s = 0.0f;
    for (int t = 1; t < TT; ++t) {
        if (ar[t] == a) {
            float v = rowred[t];
            if (v <= m) s += __expf(v - m);
            else { s = s * __expf(m - v) + 1.0f; m = v; }
        }
    }
    float v = (m == -INFINITY) ? NEGBIG : (W[a] + m + logf(s));
    out[a] = safe_out(v);
}
__global__ void k_ibins(const int* __restrict__ en, const float* __restrict__ colred,
                        const float* __restrict__ W, float* __restrict__ out) {
    int e = threadIdx.x;
    float m = -INFINITY, s = 0.0f;
    for (int j = 1; j < VV; ++j) {
        if (en[j] == e) {
            float v = colred[j];
            if (v <= m) s += __expf(v - m);
            else { s = s * __expf(m - v) + 1.0f; m = v; }
        }
    }
    float v = (m == -INFINITY) ? NEGBIG : (W[AA + e] + m + logf(s));
    out[AA + e] = safe_out(v);
}

extern "C" void kernel_launch(void* const* d_in, const int* in_sizes, int n_in,
                              void* d_out, int out_size, void* d_ws, size_t ws_size,
                              hipStream_t stream) {
    const float* W  = (const float*)d_in[0];   // weights, C floats
    const int*   ar = (const int*)d_in[1];     // ar_sent, T ints
    const int*   en = (const int*)d_in[2];     // en_sent, V ints
    float* out = (float*)d_out;

    const size_t STRIP_BYTES = (size_t)32 * LSTEPS * SH * 4;   // ~8.9 MB
    char* p = (char*)d_ws;
    float* wss     = (float*)p; p += STRIP_BYTES;
    float* a_sd    = (float*)p; p += STRIP_BYTES;
    float* alpha   = (float*)p; p += (size_t)TT * VV * 4;
    float* beta    = (float*)p; p += (size_t)TT * VV * 4;
    float* bnd     = (float*)p; p += (size_t)32 * 1024 * 4;
    unsigned* flags= (unsigned*)p; p += 32 * NSTRIP * 4;
    float* wd      = (float*)p; p += TT * 4;
    float* wi      = (float*)p; p += VV * 4;
    float* row0    = (float*)p; p += VV * 4;
    float* rowlast = (float*)p; p += VV * 4;
    float* rowred  = (float*)p; p += TT * 4;
    float* colred  = (float*)p; p += VV * 4;
    float* sbuf    = (float*)p; p += (size_t)CC * 4;
    unsigned* mkey = (unsigned*)p; p += (size_t)CC * 4;

    k_initbins<<<dim3((CC + 255) / 256), dim3(256), 0, stream>>>(mkey, sbuf, flags);
    k_prep<<<dim3(1), dim3(1024), 0, stream>>>(W, ar, en, wd, wi, row0, rowlast);
    k_wsstrip<<<dim3(LSTEPS, 32), dim3(64), 0, stream>>>(W, ar, en, wss);
    k_dp_strip<<<dim3(32), dim3(64), 0, stream>>>(wss, wd, wi, row0, rowlast, a_sd, bnd, flags);
    k_striptr<<<dim3(16, 16), dim3(256), 0, stream>>>(a_sd, alpha, 0);
    k_striptr<<<dim3(16, 16), dim3(256), 0, stream>>>(a_sd, beta, 1);
    k_rowred<<<dim3(TT - 1), dim3(256), 0, stream>>>(alpha, beta, rowred);
    k_colred<<<dim3(VV - 1), dim3(256), 0, stream>>>(alpha, beta, colred);
    k_smax<<<dim3(TT - 1), dim3(256), 0, stream>>>(alpha, beta, ar, en, mkey);
    k_ssum<<<dim3(TT - 1), dim3(256), 0, stream>>>(alpha, beta, ar, en, mkey, sbuf);
    k_sfin<<<dim3(256), dim3(256), 0, stream>>>(mkey, sbuf, W, out);
    k_dbins<<<dim3(1), dim3(256), 0, stream>>>(ar, rowred, W, out);
    k_ibins<<<dim3(1), dim3(256), 0, stream>>>(en, colred, W, out);
}

// Round 5
// 1763.108 us; speedup vs baseline: 1.7574x; 1.7574x over previous
//
#include <hip/hip_runtime.h>
#include <math.h>

#define AA 256
#define EE 256
#define CC (AA + EE + AA*EE)   // 66048
#define TT 1024
#define VV 1024
#define NSTRIP 16
#define SH 64
#define LSTEPS 1088            // 17 phases x 64 steps (padded)
#define NPHASE 17
#define NEGBIG (-3.0e38f)      // finite stand-in for -inf (ref has -inf at empty bins)

// order-preserving float->uint key for atomicMax
__device__ __forceinline__ unsigned fkey(float f) {
    unsigned u = __float_as_uint(f);
    return (u & 0x80000000u) ? ~u : (u | 0x80000000u);
}
__device__ __forceinline__ float fdec(unsigned k) {
    return __uint_as_float((k & 0x80000000u) ? (k & 0x7FFFFFFFu) : ~k);
}
#define KEY_NEGINF 0x007FFFFFu   // fkey(-inf)

__device__ __forceinline__ float safe_out(float v) {
    if (!(v > NEGBIG)) return NEGBIG;   // catches -inf, NaN
    return v;
}

// ---------------- init bins + pipeline flags ----------------
__global__ void k_initbins(unsigned* __restrict__ mkey, float* __restrict__ sbuf,
                           unsigned* __restrict__ flags) {
    int i = blockIdx.x * 256 + threadIdx.x;
    if (i < CC) { mkey[i] = 0u; sbuf[i] = 0.0f; }
    if (i < 32 * 32) flags[i] = 0u;
}

// ---------------- prep: wd, wi, row0 (prefix), rowlast (suffix) ----------------
__global__ __launch_bounds__(1024)
void k_prep(const float* __restrict__ W, const int* __restrict__ ar, const int* __restrict__ en,
            float* __restrict__ wd, float* __restrict__ wi,
            float* __restrict__ row0, float* __restrict__ rowlast) {
    __shared__ float pre[VV];
    __shared__ float suf[VV];
    int j = threadIdx.x;
    float wi_j = W[AA + en[j]];
    wi[j] = wi_j;
    wd[j] = W[ar[j]];
    float x = (j >= 1) ? wi_j : 0.0f;
    pre[j] = x;
    suf[j] = x;
    __syncthreads();
    for (int off = 1; off < VV; off <<= 1) {
        float addp = (j >= off) ? pre[j - off] : 0.0f;
        float adds = (j + off < VV) ? suf[j + off] : 0.0f;
        __syncthreads();
        pre[j] += addp;
        suf[j] += adds;
        __syncthreads();
    }
    row0[j] = pre[j];                               // row0[j] = sum wi[1..j], row0[0]=0
    rowlast[j] = (j == VV - 1) ? 0.0f : suf[j + 1]; // rowlast[j] = sum wi[j+1..V-1]
}

// ---------------- substitution weights in strip-step layout ----------------
// wss[dirb][d][r]: cell (rr=64b+r, jk=d-r).
// dir 0 (fwd): W[A+E+256*ar[rr]+en[jk]]; dir 1 (bwd): W[A+E+256*ar[1024-rr]+en[1024-jk]]
__global__ __launch_bounds__(64)
void k_wsstrip(const float* __restrict__ W, const int* __restrict__ ar, const int* __restrict__ en,
               float* __restrict__ wss) {
    int d = blockIdx.x;          // 0..1087
    int dirb = blockIdx.y;       // 0..31
    int dir = dirb >> 4, b = dirb & 15;
    int r = threadIdx.x;
    int rr = (b << 6) + r;
    int jk = d - r;
    float v = 0.0f;
    if (rr >= 1 && jk >= 1 && jk < 1024) {
        v = (dir == 0) ? W[AA + EE + (ar[rr] << 8) + en[jk]]
                       : W[AA + EE + (ar[1024 - rr] << 8) + en[1024 - jk]];
    }
    wss[((size_t)dirb * LSTEPS + d) * SH + r] = v;
}

// ---------------- pipelined strip DP: 32 blocks x 1 wave ----------------
// Blocks 0..15: forward (alpha); 16..31: backward (beta, mirrored coords).
// Lane r = row rr=64b+r; step d: col jk=d-r. Lane->lane dep via DPP wave_shr1.
// ws staged in LDS double buffer (global_load_lds), output stored row-major
// (own-row float4 every 4 steps). Inter-strip handoff: bnd + flags, 32-col chunks.
__global__ __launch_bounds__(64)
void k_dp_strip(const float* __restrict__ wss, const float* __restrict__ wd,
                const float* __restrict__ wi, const float* __restrict__ row0,
                const float* __restrict__ rowlast,
                float* __restrict__ alpha, float* __restrict__ beta,
                float* __restrict__ bnd, unsigned* __restrict__ flags) {
    __shared__ float wsb_lds[2][64 * SH];   // 32KB double buffer
    __shared__ float wi_s[1024];
    __shared__ float seed_s[1024];
    const int tid = threadIdx.x;
    const int dirb = blockIdx.x;            // 0..31
    const int dir = dirb >> 4, b = dirb & 15;
    const bool fwd = (dir == 0);
    const int rr = (b << 6) + tid;

    for (int x = tid; x < 1024; x += 64) {
        wi_s[x] = (x >= 1) ? (fwd ? wi[x] : wi[1024 - x]) : 0.0f;
        if (b == 0) seed_s[x] = fwd ? row0[x] : rowlast[1023 - x];
    }
    const float mywd = (rr >= 1) ? (fwd ? wd[rr] : wd[1024 - rr]) : 0.0f;
    const bool seedlane = (b == 0) && (tid == 0);

    float* __restrict__ orow = fwd ? (alpha + (size_t)rr * 1024)
                                   : (beta + (size_t)(1023 - rr) * 1024);
    const float* __restrict__ wsrc = wss + (size_t)dirb * LSTEPS * SH;
    float* __restrict__ bnd_me = bnd + (size_t)dirb * 1024;
    const float* __restrict__ bnd_prev = bnd + (size_t)(dirb - 1) * 1024;

    auto stage = [&](int ph) {   // issue 16KB of phase ph into buffer ph&1
        const float* g = wsrc + (size_t)ph * 64 * SH;
        #pragma unroll
        for (int i = 0; i < 16; ++i) {
            __builtin_amdgcn_global_load_lds(
                (const __attribute__((address_space(1))) void*)(g + (i << 8) + (tid << 2)),
                (__attribute__((address_space(3))) void*)(&wsb_lds[ph & 1][i << 8]),
                16, 0, 0);
        }
    };

    stage(0);

    // prologue: boundary chunk 0 + bc pipeline
    float bvals = -INFINITY;
    if (b == 0) {
        bvals = seed_s[tid & 31];
    } else {
        unsigned fidx = ((unsigned)(dirb - 1) << 5);
        while (__hip_atomic_load(&flags[fidx], __ATOMIC_ACQUIRE,
                                 __HIP_MEMORY_SCOPE_AGENT) == 0u)
            __builtin_amdgcn_s_sleep(1);
        bvals = __hip_atomic_load(&bnd_prev[tid & 31], __ATOMIC_RELAXED,
                                  __HIP_MEMORY_SCOPE_AGENT);
    }
    float bcn = __shfl(bvals, 0);

    asm volatile("s_waitcnt vmcnt(0)" ::: "memory");
    float wspipe0 = wsb_lds[0][tid];          // step 0
    float wspipe1 = wsb_lds[0][64 + tid];     // step 1

    float vm1 = -INFINITY, upprev = -INFINITY, bprev = -INFINITY;
    float h0 = -INFINITY, h1 = -INFINITY, h2 = -INFINITY;

    for (int p = 0; p < NPHASE; ++p) {
        if (p + 1 < NPHASE) stage(p + 1);
        for (int s = 0; s < 64; ++s) {
            const int d = (p << 6) + s;
            if (s == 48) asm volatile("s_waitcnt vmcnt(0)" ::: "memory");

            float bc = bcn;
#if __has_builtin(__builtin_amdgcn_update_dpp)
            float up1 = __int_as_float(__builtin_amdgcn_update_dpp(
                (int)0xFF800000, __float_as_int(vm1), 0x138 /*WAVE_SHR1*/, 0xF, 0xF, false));
#else
            float up1 = __shfl_up(vm1, 1);
#endif
            float up2 = upprev;
            if (tid == 0) { up1 = bc; up2 = bprev; }
            bprev = bc;

            float wsv = wspipe0; wspipe0 = wspipe1;
            { int dn = d + 2; dn = dn < (LSTEPS - 1) ? dn : (LSTEPS - 1);
              wspipe1 = wsb_lds[(dn >> 6) & 1][((dn & 63) << 6) + tid]; }

            const int jk = d - tid;
            const bool act = ((unsigned)jk < 1024u);
            const bool inner = act && (jk >= 1);
            float del = mywd + up1;
            float sub = inner ? (wsv + up2) : -INFINITY;
            float ins = inner ? (vm1 + wi_s[jk & 1023]) : -INFINITY;
            float m3 = fmaxf(fmaxf(del, sub), ins);
            float v = -INFINITY;
            if (m3 > -INFINITY)
                v = m3 + __logf(__expf(del - m3) + __expf(sub - m3) + __expf(ins - m3));
            if (!act) v = -INFINITY;
            if (seedlane) v = act ? bc : -INFINITY;

            if (act && (jk & 3) == 3) {      // flush 4 cols, own row (16B aligned)
                float4 o = fwd ? make_float4(h2, h1, h0, v)
                               : make_float4(v, h0, h1, h2);
                *(float4*)(orow + (fwd ? (jk - 3) : (1023 - jk))) = o;
            }
            h2 = h1; h1 = h0; h0 = v;
            upprev = up1;
            vm1 = v;

            if (tid == 63 && act) {          // producer: publish bottom row
                __hip_atomic_store(&bnd_me[jk], v, __ATOMIC_RELAXED, __HIP_MEMORY_SCOPE_AGENT);
                if ((jk & 31) == 31 && b < NSTRIP - 1)
                    __hip_atomic_store(&flags[((unsigned)dirb << 5) + (unsigned)(jk >> 5)], 1u,
                                       __ATOMIC_RELEASE, __HIP_MEMORY_SCOPE_AGENT);
            }

            if ((s & 31) == 31) {            // fetch next 32-col boundary chunk
                int dn1 = d + 1;
                if (dn1 < 1024) {
                    if (b == 0) {
                        bvals = seed_s[dn1 + (tid & 31)];
                    } else {
                        unsigned fidx = ((unsigned)(dirb - 1) << 5) + (unsigned)(dn1 >> 5);
                        while (__hip_atomic_load(&flags[fidx], __ATOMIC_ACQUIRE,
                                                 __HIP_MEMORY_SCOPE_AGENT) == 0u)
                            __builtin_amdgcn_s_sleep(1);
                        bvals = __hip_atomic_load(&bnd_prev[dn1 + (tid & 31)], __ATOMIC_RELAXED,
                                                  __HIP_MEMORY_SCOPE_AGENT);
                    }
                }
            }
            bcn = __shfl(bvals, (s + 1) & 31);
        }
    }
}

// ---------------- block reduce helpers (256 threads = 4 waves) ----------------
__device__ __forceinline__ float blk_max(float v, float* sm) {
    for (int off = 32; off > 0; off >>= 1) v = fmaxf(v, __shfl_xor(v, off));
    if ((threadIdx.x & 63) == 0) sm[threadIdx.x >> 6] = v;
    __syncthreads();
    float r = fmaxf(fmaxf(sm[0], sm[1]), fmaxf(sm[2], sm[3]));
    __syncthreads();
    return r;
}
__device__ __forceinline__ float blk_sum(float v, float* sm) {
    for (int off = 32; off > 0; off >>= 1) v += __shfl_xor(v, off);
    if ((threadIdx.x & 63) == 0) sm[threadIdx.x >> 6] = v;
    __syncthreads();
    float r = sm[0] + sm[1] + sm[2] + sm[3];
    __syncthreads();
    return r;
}

// ---------------- delete row reduction: rowred[t] = LSE_j(alpha[t-1][j]+beta[t][j]) ----------------
__global__ void k_rowred(const float* __restrict__ alpha, const float* __restrict__ beta,
                         float* __restrict__ rowred) {
    __shared__ float sm[4];
    int t = 1 + blockIdx.x;
    int tid = threadIdx.x;
    float v[4]; float m = -INFINITY;
    for (int i = 0; i < 4; ++i) {
        int j = tid + (i << 8);
        v[i] = alpha[(size_t)(t - 1) * VV + j] + beta[(size_t)t * VV + j];
        m = fmaxf(m, v[i]);
    }
    m = blk_max(m, sm);
    float s = 0.0f;
    for (int i = 0; i < 4; ++i) s += __expf(v[i] - m);
    s = blk_sum(s, sm);
    if (tid == 0) rowred[t] = m + logf(s);
}

// ---------------- insert col reduction (tiled, coalesced): colred[j] = LSE_t(alpha[t][j-1]+beta[t][j]) ----------------
__global__ __launch_bounds__(256)
void k_colred(const float* __restrict__ alpha, const float* __restrict__ beta,
              float* __restrict__ colred) {
    __shared__ float smm[4][64], sms[4][64];
    int c = threadIdx.x & 63;
    int g = threadIdx.x >> 6;
    int j = (blockIdx.x << 6) + c;
    float m = -INFINITY, s = 0.0f;
    if (j >= 1) {
        for (int t = g; t < 1024; t += 4) {
            float v = alpha[(size_t)t * 1024 + (j - 1)] + beta[(size_t)t * 1024 + j];
            if (v <= m) s += __expf(v - m);
            else { s = s * __expf(m - v) + 1.0f; m = v; }
        }
    }
    smm[g][c] = m; sms[g][c] = s;
    __syncthreads();
    if (g == 0 && j >= 1) {
        float M = m, S = s;
        for (int k = 1; k < 4; ++k) {
            float mk = smm[k][c], sk = sms[k][c];
            if (mk <= M) S += sk * __expf(mk - M);
            else { S = S * __expf(M - mk) + sk; M = mk; }
        }
        colred[j] = M + __logf(S);
    }
}

// ---------------- substitution bins: two-pass atomic LSE over (a,e) ----------------
__global__ void k_smax(const float* __restrict__ alpha, const float* __restrict__ beta,
                       const int* __restrict__ ar, const int* __restrict__ en,
                       unsigned* __restrict__ mkey) {
    int t = 1 + blockIdx.x;
    int base = AA + EE + (ar[t] << 8);
    for (int j = 1 + threadIdx.x; j <= VV - 1; j += 256) {
        float v = alpha[(size_t)(t - 1) * VV + (j - 1)] + beta[(size_t)t * VV + j];
        atomicMax(&mkey[base + en[j]], fkey(v));
    }
}
__global__ void k_ssum(const float* __restrict__ alpha, const float* __restrict__ beta,
                       const int* __restrict__ ar, const int* __restrict__ en,
                       const unsigned* __restrict__ mkey, float* __restrict__ sbuf) {
    int t = 1 + blockIdx.x;
    int base = AA + EE + (ar[t] << 8);
    for (int j = 1 + threadIdx.x; j <= VV - 1; j += 256) {
        float v = alpha[(size_t)(t - 1) * VV + (j - 1)] + beta[(size_t)t * VV + j];
        int b = base + en[j];
        atomicAdd(&sbuf[b], __expf(v - fdec(mkey[b])));
    }
}
__global__ void k_sfin(const unsigned* __restrict__ mkey, const float* __restrict__ sbuf,
                       const float* __restrict__ W, float* __restrict__ out) {
    int k = blockIdx.x * 256 + threadIdx.x;     // 0..65535
    int id = AA + EE + k;
    unsigned key = mkey[id];
    float v = (key > KEY_NEGINF) ? (W[id] + fdec(key) + logf(sbuf[id])) : NEGBIG;
    out[id] = safe_out(v);
}

// ---------------- delete / insert final binning ----------------
__global__ void k_dbins(const int* __restrict__ ar, const float* __restrict__ rowred,
                        const float* __restrict__ W, float* __restrict__ out) {
    int a = threadIdx.x;
    float m = -INFINITY, s = 0.0f;
    for (int t = 1; t < TT; ++t) {
        if (ar[t] == a) {
            float v = rowred[t];
            if (v <= m) s += __expf(v - m);
            else { s = s * __expf(m - v) + 1.0f; m = v; }
        }
    }
    float v = (m == -INFINITY) ? NEGBIG : (W[a] + m + logf(s));
    out[a] = safe_out(v);
}
__global__ void k_ibins(const int* __restrict__ en, const float* __restrict__ colred,
                        const float* __restrict__ W, float* __restrict__ out) {
    int e = threadIdx.x;
    float m = -INFINITY, s = 0.0f;
    for (int j = 1; j < VV; ++j) {
        if (en[j] == e) {
            float v = colred[j];
            if (v <= m) s += __expf(v - m);
            else { s = s * __expf(m - v) + 1.0f; m = v; }
        }
    }
    float v = (m == -INFINITY) ? NEGBIG : (W[AA + e] + m + logf(s));
    out[AA + e] = safe_out(v);
}

extern "C" void kernel_launch(void* const* d_in, const int* in_sizes, int n_in,
                              void* d_out, int out_size, void* d_ws, size_t ws_size,
                              hipStream_t stream) {
    const float* W  = (const float*)d_in[0];   // weights, C floats
    const int*   ar = (const int*)d_in[1];     // ar_sent, T ints
    const int*   en = (const int*)d_in[2];     // en_sent, V ints
    float* out = (float*)d_out;

    const size_t WSS_BYTES = (size_t)32 * LSTEPS * SH * 4;   // ~8.9 MB
    char* p = (char*)d_ws;
    float* wss     = (float*)p; p += WSS_BYTES;
    float* alpha   = (float*)p; p += (size_t)TT * VV * 4;
    float* beta    = (float*)p; p += (size_t)TT * VV * 4;
    float* bnd     = (float*)p; p += (size_t)32 * 1024 * 4;
    unsigned* flags= (unsigned*)p; p += 32 * 32 * 4;
    float* wd      = (float*)p; p += TT * 4;
    float* wi      = (float*)p; p += VV * 4;
    float* row0    = (float*)p; p += VV * 4;
    float* rowlast = (float*)p; p += VV * 4;
    float* rowred  = (float*)p; p += TT * 4;
    float* colred  = (float*)p; p += VV * 4;
    float* sbuf    = (float*)p; p += (size_t)CC * 4;
    unsigned* mkey = (unsigned*)p; p += (size_t)CC * 4;

    k_initbins<<<dim3((CC + 255) / 256), dim3(256), 0, stream>>>(mkey, sbuf, flags);
    k_prep<<<dim3(1), dim3(1024), 0, stream>>>(W, ar, en, wd, wi, row0, rowlast);
    k_wsstrip<<<dim3(LSTEPS, 32), dim3(64), 0, stream>>>(W, ar, en, wss);
    k_dp_strip<<<dim3(32), dim3(64), 0, stream>>>(wss, wd, wi, row0, rowlast,
                                                  alpha, beta, bnd, flags);
    k_rowred<<<dim3(TT - 1), dim3(256), 0, stream>>>(alpha, beta, rowred);
    k_colred<<<dim3(16), dim3(256), 0, stream>>>(alpha, beta, colred);
    k_smax<<<dim3(TT - 1), dim3(256), 0, stream>>>(alpha, beta, ar, en, mkey);
    k_ssum<<<dim3(TT - 1), dim3(256), 0, stream>>>(alpha, beta, ar, en, mkey, sbuf);
    k_sfin<<<dim3(256), dim3(256), 0, stream>>>(mkey, sbuf, W, out);
    k_dbins<<<dim3(1), dim3(256), 0, stream>>>(ar, rowred, W, out);
    k_ibins<<<dim3(1), dim3(256), 0, stream>>>(en, colred, W, out);
}

// Round 6
// 766.330 us; speedup vs baseline: 4.0432x; 2.3007x over previous
//
#include <hip/hip_runtime.h>
#include <math.h>

#define AA 256
#define EE 256
#define CC (AA + EE + AA*EE)   // 66048
#define TT 1024
#define VV 1024
#define NSTRIP 16
#define NCHUNK 34              // 34*32 = 1088 steps
#define NEGBIG (-3.0e38f)      // finite stand-in for -inf in outputs
#define INVLN2 1.44269504088896340736f
#define LN2F   0.69314718055994530942f
#define SENT   0x7FC00001u     // NaN-payload sentinel for bnd
#define NINF   (-__builtin_inff())

// order-preserving float->uint key for atomicMax
__device__ __forceinline__ unsigned fkey(float f) {
    unsigned u = __float_as_uint(f);
    return (u & 0x80000000u) ? ~u : (u | 0x80000000u);
}
__device__ __forceinline__ float fdec(unsigned k) {
    return __uint_as_float((k & 0x80000000u) ? (k & 0x7FFFFFFFu) : ~k);
}
#define KEY_NEGINF 0x007FFFFFu   // fkey(-inf)

__device__ __forceinline__ float safe_out(float v) {
    if (!(v > NEGBIG)) return NEGBIG;   // catches -inf, NaN
    return v;
}

// ---------------- init bins + bnd sentinel ----------------
__global__ void k_initbins(unsigned* __restrict__ mkey, float* __restrict__ sbuf,
                           unsigned* __restrict__ bndu) {
    int i = blockIdx.x * 256 + threadIdx.x;
    if (i < CC) { mkey[i] = 0u; sbuf[i] = 0.0f; }
    if (i < 32 * 1024) bndu[i] = SENT;
}

// ---------------- W2 = W * 1/ln2 (log2 domain) ----------------
__global__ void k_wscale(const float* __restrict__ W, float* __restrict__ W2) {
    int i = blockIdx.x * 256 + threadIdx.x;
    if (i < CC) W2[i] = W[i] * INVLN2;
}

// ---------------- prep (log2 domain): wd2, wi2, row02, rowlast2 ----------------
__global__ __launch_bounds__(1024)
void k_prep(const float* __restrict__ W, const int* __restrict__ ar, const int* __restrict__ en,
            float* __restrict__ wd2, float* __restrict__ wi2,
            float* __restrict__ row02, float* __restrict__ rowlast2) {
    __shared__ float pre[VV];
    __shared__ float suf[VV];
    int j = threadIdx.x;
    float wi_j = W[AA + en[j]] * INVLN2;
    wi2[j] = wi_j;
    wd2[j] = W[ar[j]] * INVLN2;
    float x = (j >= 1) ? wi_j : 0.0f;
    pre[j] = x;
    suf[j] = x;
    __syncthreads();
    for (int off = 1; off < VV; off <<= 1) {
        float addp = (j >= off) ? pre[j - off] : 0.0f;
        float adds = (j + off < VV) ? suf[j + off] : 0.0f;
        __syncthreads();
        pre[j] += addp;
        suf[j] += adds;
        __syncthreads();
    }
    row02[j] = pre[j];
    rowlast2[j] = (j == VV - 1) ? 0.0f : suf[j + 1];
}

// ---------------- pipelined strip DP: 32 blocks x 1 wave, log2 domain ----------------
// Blocks 0..15 forward (alpha), 16..31 backward (beta, mirrored). Lane r = row rr=64b+r,
// step d: col jk=d-tid. Lane dep via DPP wave_shr1 (lane0 takes boundary via DPP old).
// ws gathered per-lane from L2-hot W2, 4 steps ahead. Sentinel-based boundary sync.
__global__ __launch_bounds__(64)
void k_dp_strip(const float* __restrict__ W2, const int* __restrict__ ar,
                const int* __restrict__ en,
                const float* __restrict__ wd2, const float* __restrict__ wi2,
                const float* __restrict__ row02, const float* __restrict__ rowlast2,
                float* __restrict__ alpha, float* __restrict__ beta,
                float* __restrict__ bnd) {
    __shared__ float wi_s[64 + 1088 + 16];
    __shared__ int   en_s[64 + 1088 + 16];
    __shared__ float seed_s[1024];
    const int tid = threadIdx.x;
    const int dirb = blockIdx.x;            // 0..31
    const int dir = dirb >> 4, b = dirb & 15;
    const bool fwd = (dir == 0);
    const bool seed = (b == 0);
    const int rr = (b << 6) + tid;

    for (int x = tid; x < 64 + 1088 + 16; x += 64) {
        int col = x - 64;
        bool valid = (col >= 1 && col <= 1023);
        wi_s[x] = valid ? wi2[fwd ? col : 1024 - col] : 0.0f;
        en_s[x] = valid ? en[fwd ? col : 1024 - col] : 0;
    }
    if (seed) for (int x = tid; x < 1024; x += 64)
        seed_s[x] = fwd ? row02[x] : rowlast2[1023 - x];
    __syncthreads();   // LDS init (single wave, but cheap & safe)

    const int r_src = fwd ? rr : (1024 - rr);
    const float mywd2 = (rr >= 1) ? wd2[r_src] : 0.0f;
    const int arofs = AA + EE + ((rr >= 1) ? (ar[r_src] << 8) : 0);
    const int outrow = fwd ? (rr << 10) : ((1023 - rr) << 10);
    float* __restrict__ obase = fwd ? alpha : beta;
    float* __restrict__ bnd_me = bnd + (size_t)dirb * 1024;
    const float* __restrict__ bnd_prev = bnd + (size_t)(dirb - 1) * 1024;
    const bool seedlane = seed && (tid == 0);
    const int t3 = (tid + 3) & 3;           // store when (k&3)==t3

    float vm1 = NINF, upprev = NINF;
    float h0 = NINF, h1 = NINF, h2 = NINF;
    float wsv[8], wiv[8]; int env[8];
    // prime pipelines (padded LDS makes all indices safe)
    #pragma unroll
    for (int s = 0; s < 8; ++s) env[s] = en_s[64 - tid + s];
    #pragma unroll
    for (int s = 0; s < 4; ++s) wiv[s] = wi_s[64 - tid + s];
    #pragma unroll
    for (int s = 0; s < 4; ++s) wsv[s] = W2[arofs + env[s]];
    float bvals = NINF;

    for (int c = 0; c < NCHUNK; ++c) {
        const int dbase = c << 5;
        if (c <= 31) {                       // fetch boundary chunk (cols dbase..dbase+31)
            if (seed) {
                bvals = seed_s[dbase + (tid & 31)];
            } else {
                const unsigned* src = (const unsigned*)(bnd_prev + dbase + (tid & 31));
                unsigned x = __hip_atomic_load(src, __ATOMIC_RELAXED, __HIP_MEMORY_SCOPE_AGENT);
                while (__ballot(x != SENT) != ~0ull) {
                    __builtin_amdgcn_s_sleep(2);
                    x = __hip_atomic_load(src, __ATOMIC_RELAXED, __HIP_MEMORY_SCOPE_AGENT);
                }
                bvals = __uint_as_float(x);
            }
        }
        #pragma unroll
        for (int k = 0; k < 32; ++k) {
            const int d = dbase + k;
            const int jk = d - tid;
            float bc = __int_as_float(__builtin_amdgcn_readlane(__float_as_int(bvals), k));
            float up1 = __int_as_float(__builtin_amdgcn_update_dpp(
                __float_as_int(bc), __float_as_int(vm1), 0x138 /*WAVE_SHR1*/, 0xF, 0xF, false));
            float del = mywd2 + up1;
            float sub = wsv[k & 7] + upprev;          // -inf guards fall out naturally
            float ins = vm1 + wiv[k & 7];
            float m3 = fmaxf(fmaxf(del, sub), ins);
            float v = m3 + __log2f(exp2f(del - m3) + exp2f(sub - m3) + exp2f(ins - m3));
            const bool act = ((unsigned)jk < 1024u);
            v = act ? v : NINF;
            v = seedlane ? (act ? bc : NINF) : v;

            // software pipelines (off critical path)
            wiv[(k + 4) & 7] = wi_s[64 - tid + d + 4];
            env[(k + 8) & 7] = en_s[64 - tid + d + 8];
            wsv[(k + 4) & 7] = W2[arofs + env[(k + 4) & 7]];

            // boundary publish: lane 63, fire-and-forget relaxed store (data IS the flag)
            if (tid == 63 && act)
                __hip_atomic_store((unsigned*)(bnd_me + jk), __float_as_uint(v),
                                   __ATOMIC_RELAXED, __HIP_MEMORY_SCOPE_AGENT);
            // row-major output: own row, float4 per 4 own-steps
            if (((k & 3) == t3) && act && jk >= 3) {
                float4 o = fwd ? make_float4(h2, h1, h0, v) : make_float4(v, h0, h1, h2);
                *(float4*)(obase + outrow + (fwd ? (jk - 3) : (1023 - jk))) = o;
            }
            h2 = h1; h1 = h0; h0 = v;
            upprev = up1; vm1 = v;
        }
    }
}

// ---------------- block reduce helpers (256 threads = 4 waves) ----------------
__device__ __forceinline__ float blk_max(float v, float* sm) {
    for (int off = 32; off > 0; off >>= 1) v = fmaxf(v, __shfl_xor(v, off));
    if ((threadIdx.x & 63) == 0) sm[threadIdx.x >> 6] = v;
    __syncthreads();
    float r = fmaxf(fmaxf(sm[0], sm[1]), fmaxf(sm[2], sm[3]));
    __syncthreads();
    return r;
}
__device__ __forceinline__ float blk_sum(float v, float* sm) {
    for (int off = 32; off > 0; off >>= 1) v += __shfl_xor(v, off);
    if ((threadIdx.x & 63) == 0) sm[threadIdx.x >> 6] = v;
    __syncthreads();
    float r = sm[0] + sm[1] + sm[2] + sm[3];
    __syncthreads();
    return r;
}

// ---------------- delete row reduction (log2): rowred[t] = LSE2_j(alpha[t-1][j]+beta[t][j]) ----------------
__global__ void k_rowred(const float* __restrict__ alpha, const float* __restrict__ beta,
                         float* __restrict__ rowred) {
    __shared__ float sm[4];
    int t = 1 + blockIdx.x;
    int tid = threadIdx.x;
    float v[4]; float m = NINF;
    for (int i = 0; i < 4; ++i) {
        int j = tid + (i << 8);
        v[i] = alpha[(size_t)(t - 1) * VV + j] + beta[(size_t)t * VV + j];
        m = fmaxf(m, v[i]);
    }
    m = blk_max(m, sm);
    float s = 0.0f;
    for (int i = 0; i < 4; ++i) s += exp2f(v[i] - m);
    s = blk_sum(s, sm);
    if (tid == 0) rowred[t] = m + __log2f(s);
}

// ---------------- insert col reduction, stage 1: partials over 128-row bands ----------------
__global__ __launch_bounds__(256)
void k_colpart(const float* __restrict__ alpha, const float* __restrict__ beta,
               float* __restrict__ cpm, float* __restrict__ cps) {
    __shared__ float smm[4][64], sms[4][64];
    int c = threadIdx.x & 63;
    int g = threadIdx.x >> 6;
    int j = (blockIdx.x << 6) + c;
    int t0 = blockIdx.y << 7;
    float m = NINF, s = 0.0f;
    if (j >= 1) {
        for (int t = t0 + g; t < t0 + 128; t += 4) {
            float v = alpha[(size_t)t * 1024 + (j - 1)] + beta[(size_t)t * 1024 + j];
            if (v <= m) s += exp2f(v - m);
            else { s = s * exp2f(m - v) + 1.0f; m = v; }
        }
    }
    smm[g][c] = m; sms[g][c] = s;
    __syncthreads();
    if (g == 0) {
        float M = m, S = s;
        for (int k = 1; k < 4; ++k) {
            float mk = smm[k][c], sk = sms[k][c];
            if (mk <= M) S += sk * exp2f(mk - M);
            else { S = S * exp2f(M - mk) + sk; M = mk; }
        }
        cpm[(size_t)blockIdx.y * 1024 + j] = M;
        cps[(size_t)blockIdx.y * 1024 + j] = S;
    }
}
// stage 2: merge 8 bands
__global__ void k_colfin(const float* __restrict__ cpm, const float* __restrict__ cps,
                         float* __restrict__ colred) {
    int j = blockIdx.x * 256 + threadIdx.x;
    float M = NINF, S = 0.0f;
    for (int k = 0; k < 8; ++k) {
        float mk = cpm[(size_t)k * 1024 + j], sk = cps[(size_t)k * 1024 + j];
        if (mk <= M) S += sk * exp2f(mk - M);
        else { S = S * exp2f(M - mk) + sk; M = mk; }
    }
    colred[j] = (j >= 1) ? (M + __log2f(S)) : NINF;
}

// ---------------- substitution bins: two-pass atomic LSE over (a,e), log2 ----------------
__global__ void k_smax(const float* __restrict__ alpha, const float* __restrict__ beta,
                       const int* __restrict__ ar, const int* __restrict__ en,
                       unsigned* __restrict__ mkey) {
    int t = 1 + blockIdx.x;
    int base = AA + EE + (ar[t] << 8);
    for (int j = 1 + threadIdx.x; j <= VV - 1; j += 256) {
        float v = alpha[(size_t)(t - 1) * VV + (j - 1)] + beta[(size_t)t * VV + j];
        atomicMax(&mkey[base + en[j]], fkey(v));
    }
}
__global__ void k_ssum(const float* __restrict__ alpha, const float* __restrict__ beta,
                       const int* __restrict__ ar, const int* __restrict__ en,
                       const unsigned* __restrict__ mkey, float* __restrict__ sbuf) {
    int t = 1 + blockIdx.x;
    int base = AA + EE + (ar[t] << 8);
    for (int j = 1 + threadIdx.x; j <= VV - 1; j += 256) {
        float v = alpha[(size_t)(t - 1) * VV + (j - 1)] + beta[(size_t)t * VV + j];
        int b = base + en[j];
        atomicAdd(&sbuf[b], exp2f(v - fdec(mkey[b])));
    }
}
__global__ void k_sfin(const unsigned* __restrict__ mkey, const float* __restrict__ sbuf,
                       const float* __restrict__ W, float* __restrict__ out) {
    int k = blockIdx.x * 256 + threadIdx.x;
    int id = AA + EE + k;
    unsigned key = mkey[id];
    float v = (key > KEY_NEGINF) ? (W[id] + LN2F * (fdec(key) + __log2f(sbuf[id]))) : NEGBIG;
    out[id] = safe_out(v);
}

// ---------------- delete / insert final binning (LDS-staged) ----------------
__global__ __launch_bounds__(256)
void k_dbins(const int* __restrict__ ar, const float* __restrict__ rowred,
             const float* __restrict__ W, float* __restrict__ out) {
    __shared__ float rv[1024]; __shared__ int av[1024];
    int tid = threadIdx.x;
    for (int x = tid; x < 1024; x += 256) { rv[x] = rowred[x]; av[x] = ar[x]; }
    __syncthreads();
    float m = NINF, s = 0.0f;
    for (int t = 1; t < TT; ++t) {
        if (av[t] == tid) {
            float v = rv[t];
            if (v <= m) s += exp2f(v - m);
            else { s = s * exp2f(m - v) + 1.0f; m = v; }
        }
    }
    float v = (m == NINF) ? NEGBIG : (W[tid] + LN2F * (m + __log2f(s)));
    out[tid] = safe_out(v);
}
__global__ __launch_bounds__(256)
void k_ibins(const int* __restrict__ en, const float* __restrict__ colred,
             const float* __restrict__ W, float* __restrict__ out) {
    __shared__ float cv[1024]; __shared__ int ev[1024];
    int tid = threadIdx.x;
    for (int x = tid; x < 1024; x += 256) { cv[x] = colred[x]; ev[x] = en[x]; }
    __syncthreads();
    float m = NINF, s = 0.0f;
    for (int j = 1; j < VV; ++j) {
        if (ev[j] == tid) {
            float v = cv[j];
            if (v <= m) s += exp2f(v - m);
            else { s = s * exp2f(m - v) + 1.0f; m = v; }
        }
    }
    float v = (m == NINF) ? NEGBIG : (W[AA + tid] + LN2F * (m + __log2f(s)));
    out[AA + tid] = safe_out(v);
}

extern "C" void kernel_launch(void* const* d_in, const int* in_sizes, int n_in,
                              void* d_out, int out_size, void* d_ws, size_t ws_size,
                              hipStream_t stream) {
    const float* W  = (const float*)d_in[0];
    const int*   ar = (const int*)d_in[1];
    const int*   en = (const int*)d_in[2];
    float* out = (float*)d_out;

    char* p = (char*)d_ws;
    float* W2      = (float*)p; p += (size_t)CC * 4;
    float* alpha   = (float*)p; p += (size_t)TT * VV * 4;
    float* beta    = (float*)p; p += (size_t)TT * VV * 4;
    float* bnd     = (float*)p; p += (size_t)32 * 1024 * 4;
    float* wd2     = (float*)p; p += TT * 4;
    float* wi2     = (float*)p; p += VV * 4;
    float* row02   = (float*)p; p += VV * 4;
    float* rowlast2= (float*)p; p += VV * 4;
    float* rowred  = (float*)p; p += TT * 4;
    float* colred  = (float*)p; p += VV * 4;
    float* cpm     = (float*)p; p += (size_t)8 * 1024 * 4;
    float* cps     = (float*)p; p += (size_t)8 * 1024 * 4;
    float* sbuf    = (float*)p; p += (size_t)CC * 4;
    unsigned* mkey = (unsigned*)p; p += (size_t)CC * 4;

    k_initbins<<<dim3((CC + 255) / 256), dim3(256), 0, stream>>>(mkey, sbuf, (unsigned*)bnd);
    k_wscale<<<dim3((CC + 255) / 256), dim3(256), 0, stream>>>(W, W2);
    k_prep<<<dim3(1), dim3(1024), 0, stream>>>(W, ar, en, wd2, wi2, row02, rowlast2);
    k_dp_strip<<<dim3(32), dim3(64), 0, stream>>>(W2, ar, en, wd2, wi2, row02, rowlast2,
                                                  alpha, beta, bnd);
    k_rowred<<<dim3(TT - 1), dim3(256), 0, stream>>>(alpha, beta, rowred);
    k_colpart<<<dim3(16, 8), dim3(256), 0, stream>>>(alpha, beta, cpm, cps);
    k_colfin<<<dim3(4), dim3(256), 0, stream>>>(cpm, cps, colred);
    k_smax<<<dim3(TT - 1), dim3(256), 0, stream>>>(alpha, beta, ar, en, mkey);
    k_ssum<<<dim3(TT - 1), dim3(256), 0, stream>>>(alpha, beta, ar, en, mkey, sbuf);
    k_sfin<<<dim3(256), dim3(256), 0, stream>>>(mkey, sbuf, W, out);
    k_dbins<<<dim3(1), dim3(256), 0, stream>>>(ar, rowred, W, out);
    k_ibins<<<dim3(1), dim3(256), 0, stream>>>(en, colred, W, out);
}

// Round 7
// 599.393 us; speedup vs baseline: 5.1693x; 1.2785x over previous
//
#include <hip/hip_runtime.h>
#include <math.h>

#define AA 256
#define EE 256
#define CC (AA + EE + AA*EE)   // 66048
#define TT 1024
#define VV 1024
#define NCHUNK 34              // 34*32 = 1088 steps
#define NEGBIG (-3.0e38f)      // finite stand-in for -inf in outputs
#define INVLN2 1.44269504088896340736f
#define LN2F   0.69314718055994530942f
#define SENT   0x7FC00001u     // NaN-payload sentinel for bnd
#define NINF   (-__builtin_inff())

// order-preserving float->uint key for atomicMax
__device__ __forceinline__ unsigned fkey(float f) {
    unsigned u = __float_as_uint(f);
    return (u & 0x80000000u) ? ~u : (u | 0x80000000u);
}
__device__ __forceinline__ float fdec(unsigned k) {
    return __uint_as_float((k & 0x80000000u) ? (k & 0x7FFFFFFFu) : ~k);
}
#define KEY_NEGINF 0x007FFFFFu   // fkey(-inf)

__device__ __forceinline__ float safe_out(float v) {
    if (!(v > NEGBIG)) return NEGBIG;   // catches -inf, NaN
    return v;
}

// ---------------- init: bins + bnd sentinel + W2 = W/ln2 ----------------
__global__ void k_init(const float* __restrict__ W, float* __restrict__ W2,
                       unsigned* __restrict__ mkey, float* __restrict__ sbuf,
                       unsigned* __restrict__ bndu) {
    int i = blockIdx.x * 256 + threadIdx.x;
    if (i < CC) { mkey[i] = 0u; sbuf[i] = 0.0f; W2[i] = W[i] * INVLN2; }
    if (i < 32 * 1024) bndu[i] = SENT;
}

// ---------------- pipelined strip DP: 32 blocks x 1 wave, log2 domain ----------------
// Blocks 0..15 forward (alpha), 16..31 backward (beta, mirrored). Lane = row rr=64b+tid,
// step d: col jk=d-tid. Lane dep via DPP wave_shr1 (lane0 takes boundary via DPP old).
// Substitution weights staged per-block in LDS (64 rows x 256 entries = 64KB),
// per-step read ws_lds[e*64+tid] is bank-conflict-free. No global loads in the loop.
__global__ __launch_bounds__(64)
void k_dp_strip(const float* __restrict__ W2, const int* __restrict__ ar,
                const int* __restrict__ en,
                float* __restrict__ alpha, float* __restrict__ beta,
                float* __restrict__ bnd) {
    __shared__ float ws_lds[256 * 64];          // [e][row], 64KB
    __shared__ float wi_s[64 + 1088 + 16];
    __shared__ int   en_s[64 + 1088 + 16];
    __shared__ float seed_s[1024];
    const int tid = threadIdx.x;
    const int dirb = blockIdx.x;                // 0..31
    const int dir = dirb >> 4, b = dirb & 15;
    const bool fwd = (dir == 0);
    const bool seed = (b == 0);
    const int rr = (b << 6) + tid;

    for (int x = tid; x < 64 + 1088 + 16; x += 64) {
        int col = x - 64;
        bool valid = (col >= 1 && col <= 1023);
        int e = valid ? en[fwd ? col : 1024 - col] : 0;
        en_s[x] = e;
        wi_s[x] = valid ? W2[AA + e] : 0.0f;
    }

    const int r_src = (rr >= 1) ? (fwd ? rr : (1024 - rr)) : 0;
    const float mywd2 = (rr >= 1) ? W2[ar[r_src]] : 0.0f;
    // stage this lane's substitution row into LDS [e][tid]
    {
        const float* wrow = W2 + AA + EE + ((rr >= 1) ? (ar[r_src] << 8) : 0);
        #pragma unroll 8
        for (int i = 0; i < 64; ++i) {
            float4 w = *(const float4*)(wrow + (i << 2));
            ws_lds[((i << 2) + 0) * 64 + tid] = w.x;
            ws_lds[((i << 2) + 1) * 64 + tid] = w.y;
            ws_lds[((i << 2) + 2) * 64 + tid] = w.z;
            ws_lds[((i << 2) + 3) * 64 + tid] = w.w;
        }
    }

    if (seed) {   // seed_s[x] = sum_{c=1..x} wi_s[64+c]  (row0 fwd / rowlast-mirrored bwd)
        float loc[16]; float s = 0.0f;
        #pragma unroll
        for (int i = 0; i < 16; ++i) {
            int x = (tid << 4) + i;
            float w = (x >= 1) ? wi_s[64 + x] : 0.0f;
            s += w; loc[i] = s;
        }
        float cum = s;
        for (int off = 1; off < 64; off <<= 1) {
            float tt = __shfl_up(cum, off);
            if (tid >= off) cum += tt;
        }
        float excl = cum - s;
        #pragma unroll
        for (int i = 0; i < 16; ++i) seed_s[(tid << 4) + i] = excl + loc[i];
    }
    __syncthreads();

    const int outrow = fwd ? (rr << 10) : ((1023 - rr) << 10);
    float* __restrict__ obase = fwd ? alpha : beta;
    float* __restrict__ bnd_me = bnd + (size_t)dirb * 1024;
    const float* __restrict__ bnd_prev = bnd + (size_t)(dirb - 1) * 1024;
    const bool seedlane = seed && (tid == 0);
    const int t3 = (tid + 3) & 3;               // store when (k&3)==t3

    float vm1 = NINF, upprev = NINF;
    float h0 = NINF, h1 = NINF, h2 = NINF;
    float wsv[8], wiv[8]; int env[8];
    #pragma unroll
    for (int s = 0; s < 8; ++s) env[s] = en_s[64 - tid + s];
    #pragma unroll
    for (int s = 0; s < 4; ++s) wiv[s] = wi_s[64 - tid + s];
    #pragma unroll
    for (int s = 0; s < 4; ++s) wsv[s] = ws_lds[(env[s] << 6) + tid];

    #define FETCH(c) __hip_atomic_load((const unsigned*)(bnd_prev + ((c) << 5) + (tid & 31)), \
                                       __ATOMIC_RELAXED, __HIP_MEMORY_SCOPE_AGENT)
    float bvals = NINF;
    unsigned bpend = SENT;
    if (!seed) bpend = FETCH(0);

    for (int c = 0; c < NCHUNK; ++c) {
        const int dbase = c << 5;
        if (c <= 31) {
            if (seed) {
                bvals = seed_s[dbase + (tid & 31)];
            } else {
                unsigned x = bpend;
                while (__ballot(x != SENT) != ~0ull) {
                    __builtin_amdgcn_s_sleep(1);
                    x = FETCH(c);
                }
                bvals = __uint_as_float(x);
                if (c < 31) bpend = FETCH(c + 1);
            }
        }
        #pragma unroll
        for (int k = 0; k < 32; ++k) {
            const int d = dbase + k;
            const int jk = d - tid;
            float bc = __int_as_float(__builtin_amdgcn_readlane(__float_as_int(bvals), k));
            float up1 = __int_as_float(__builtin_amdgcn_update_dpp(
                __float_as_int(bc), __float_as_int(vm1), 0x138 /*WAVE_SHR1*/, 0xF, 0xF, false));
            float del = mywd2 + up1;
            float sub = wsv[k & 7] + upprev;        // -inf guards fall out naturally
            float ins = vm1 + wiv[k & 7];
            float m3 = fmaxf(fmaxf(del, sub), ins);
            float v = m3 + __log2f(exp2f(del - m3) + exp2f(sub - m3) + exp2f(ins - m3));
            const bool act = ((unsigned)jk < 1024u);
            v = act ? v : NINF;
            v = seedlane ? (act ? bc : NINF) : v;

            // software pipelines (LDS only, off critical path)
            wiv[(k + 4) & 7] = wi_s[64 - tid + d + 4];
            env[(k + 8) & 7] = en_s[64 - tid + d + 8];
            wsv[(k + 4) & 7] = ws_lds[(env[(k + 4) & 7] << 6) + tid];

            // boundary publish: lane 63, fire-and-forget relaxed store (data IS the flag)
            if (tid == 63 && act)
                __hip_atomic_store((unsigned*)(bnd_me + jk), __float_as_uint(v),
                                   __ATOMIC_RELAXED, __HIP_MEMORY_SCOPE_AGENT);
            // row-major output: own row, float4 per 4 own-steps
            if (((k & 3) == t3) && act && jk >= 3) {
                float4 o = fwd ? make_float4(h2, h1, h0, v) : make_float4(v, h0, h1, h2);
                *(float4*)(obase + outrow + (fwd ? (jk - 3) : (1023 - jk))) = o;
            }
            h2 = h1; h1 = h0; h0 = v;
            upprev = up1; vm1 = v;
        }
    }
    #undef FETCH
}

// ---------------- block reduce helpers (256 threads = 4 waves) ----------------
__device__ __forceinline__ float blk_max(float v, float* sm) {
    for (int off = 32; off > 0; off >>= 1) v = fmaxf(v, __shfl_xor(v, off));
    if ((threadIdx.x & 63) == 0) sm[threadIdx.x >> 6] = v;
    __syncthreads();
    float r = fmaxf(fmaxf(sm[0], sm[1]), fmaxf(sm[2], sm[3]));
    __syncthreads();
    return r;
}
__device__ __forceinline__ float blk_sum(float v, float* sm) {
    for (int off = 32; off > 0; off >>= 1) v += __shfl_xor(v, off);
    if ((threadIdx.x & 63) == 0) sm[threadIdx.x >> 6] = v;
    __syncthreads();
    float r = sm[0] + sm[1] + sm[2] + sm[3];
    __syncthreads();
    return r;
}

// ---------------- fused: rowred[t] (delete LSE) + substitution atomicMax ----------------
__global__ __launch_bounds__(256)
void k_red1(const float* __restrict__ alpha, const float* __restrict__ beta,
            const int* __restrict__ ar, const int* __restrict__ en,
            float* __restrict__ rowred, unsigned* __restrict__ mkey) {
    __shared__ float sm[4];
    int t = 1 + blockIdx.x;
    int tid = threadIdx.x;
    int base = AA + EE + (ar[t] << 8);
    float v[4]; float m = NINF;
    #pragma unroll
    for (int i = 0; i < 4; ++i) {
        int j = tid + (i << 8);
        float b_ = beta[(size_t)t * VV + j];
        v[i] = alpha[(size_t)(t - 1) * VV + j] + b_;
        m = fmaxf(m, v[i]);
        if (j >= 1) {
            float vs = alpha[(size_t)(t - 1) * VV + (j - 1)] + b_;
            atomicMax(&mkey[base + en[j]], fkey(vs));
        }
    }
    m = blk_max(m, sm);
    float s = 0.0f;
    #pragma unroll
    for (int i = 0; i < 4; ++i) s += exp2f(v[i] - m);
    s = blk_sum(s, sm);
    if (tid == 0) rowred[t] = m + __log2f(s);
}

// ---------------- insert col reduction, stage 1: partials over 128-row bands ----------------
__global__ __launch_bounds__(256)
void k_colpart(const float* __restrict__ alpha, const float* __restrict__ beta,
               float* __restrict__ cpm, float* __restrict__ cps) {
    __shared__ float smm[4][64], sms[4][64];
    int c = threadIdx.x & 63;
    int g = threadIdx.x >> 6;
    int j = (blockIdx.x << 6) + c;
    int t0 = blockIdx.y << 7;
    float m = NINF, s = 0.0f;
    if (j >= 1) {
        for (int t = t0 + g; t < t0 + 128; t += 4) {
            float v = alpha[(size_t)t * 1024 + (j - 1)] + beta[(size_t)t * 1024 + j];
            if (v <= m) s += exp2f(v - m);
            else { s = s * exp2f(m - v) + 1.0f; m = v; }
        }
    }
    smm[g][c] = m; sms[g][c] = s;
    __syncthreads();
    if (g == 0) {
        float M = m, S = s;
        for (int k = 1; k < 4; ++k) {
            float mk = smm[k][c], sk = sms[k][c];
            if (mk <= M) S += sk * exp2f(mk - M);
            else { S = S * exp2f(M - mk) + sk; M = mk; }
        }
        cpm[(size_t)blockIdx.y * 1024 + j] = M;
        cps[(size_t)blockIdx.y * 1024 + j] = S;
    }
}
// stage 2: merge 8 bands
__global__ void k_colfin(const float* __restrict__ cpm, const float* __restrict__ cps,
                         float* __restrict__ colred) {
    int j = blockIdx.x * 256 + threadIdx.x;
    float M = NINF, S = 0.0f;
    for (int k = 0; k < 8; ++k) {
        float mk = cpm[(size_t)k * 1024 + j], sk = cps[(size_t)k * 1024 + j];
        if (mk <= M) S += sk * exp2f(mk - M);
        else { S = S * exp2f(M - mk) + sk; M = mk; }
    }
    colred[j] = (j >= 1) ? (M + __log2f(S)) : NINF;
}

// ---------------- substitution bins: sum pass (needs mkey) ----------------
__global__ void k_ssum(const float* __restrict__ alpha, const float* __restrict__ beta,
                       const int* __restrict__ ar, const int* __restrict__ en,
                       const unsigned* __restrict__ mkey, float* __restrict__ sbuf) {
    int t = 1 + blockIdx.x;
    int base = AA + EE + (ar[t] << 8);
    for (int j = 1 + threadIdx.x; j <= VV - 1; j += 256) {
        float v = alpha[(size_t)(t - 1) * VV + (j - 1)] + beta[(size_t)t * VV + j];
        int b = base + en[j];
        atomicAdd(&sbuf[b], exp2f(v - fdec(mkey[b])));
    }
}

// ---------------- finalize: sub bins (blocks 0..255), dbins (256), ibins (257) ----------------
__global__ __launch_bounds__(256)
void k_fin(const unsigned* __restrict__ mkey, const float* __restrict__ sbuf,
           const float* __restrict__ W, const int* __restrict__ ar,
           const int* __restrict__ en, const float* __restrict__ rowred,
           const float* __restrict__ colred, float* __restrict__ out) {
    __shared__ float fv[1024];
    __shared__ int   iv[1024];
    int blk = blockIdx.x;
    int tid = threadIdx.x;
    if (blk < 256) {
        int id = AA + EE + blk * 256 + tid;
        unsigned key = mkey[id];
        float v = (key > KEY_NEGINF) ? (W[id] + LN2F * (fdec(key) + __log2f(sbuf[id]))) : NEGBIG;
        out[id] = safe_out(v);
        return;
    }
    const bool isd = (blk == 256);
    for (int x = tid; x < 1024; x += 256) {
        fv[x] = isd ? rowred[x] : colred[x];
        iv[x] = isd ? ar[x] : en[x];
    }
    __syncthreads();
    float m = NINF, s = 0.0f;
    for (int t = 1; t < 1024; ++t) {
        if (iv[t] == tid) {
            float v = fv[t];
            if (v <= m) s += exp2f(v - m);
            else { s = s * exp2f(m - v) + 1.0f; m = v; }
        }
    }
    int oid = isd ? tid : (AA + tid);
    float v = (m == NINF) ? NEGBIG : (W[oid] + LN2F * (m + __log2f(s)));
    out[oid] = safe_out(v);
}

extern "C" void kernel_launch(void* const* d_in, const int* in_sizes, int n_in,
                              void* d_out, int out_size, void* d_ws, size_t ws_size,
                              hipStream_t stream) {
    const float* W  = (const float*)d_in[0];
    const int*   ar = (const int*)d_in[1];
    const int*   en = (const int*)d_in[2];
    float* out = (float*)d_out;

    char* p = (char*)d_ws;
    float* W2      = (float*)p; p += (size_t)CC * 4;
    float* alpha   = (float*)p; p += (size_t)TT * VV * 4;
    float* beta    = (float*)p; p += (size_t)TT * VV * 4;
    float* bnd     = (float*)p; p += (size_t)32 * 1024 * 4;
    float* rowred  = (float*)p; p += TT * 4;
    float* colred  = (float*)p; p += VV * 4;
    float* cpm     = (float*)p; p += (size_t)8 * 1024 * 4;
    float* cps     = (float*)p; p += (size_t)8 * 1024 * 4;
    float* sbuf    = (float*)p; p += (size_t)CC * 4;
    unsigned* mkey = (unsigned*)p; p += (size_t)CC * 4;

    k_init<<<dim3((CC + 255) / 256), dim3(256), 0, stream>>>(W, W2, mkey, sbuf, (unsigned*)bnd);
    k_dp_strip<<<dim3(32), dim3(64), 0, stream>>>(W2, ar, en, alpha, beta, bnd);
    k_red1<<<dim3(TT - 1), dim3(256), 0, stream>>>(alpha, beta, ar, en, rowred, mkey);
    k_colpart<<<dim3(16, 8), dim3(256), 0, stream>>>(alpha, beta, cpm, cps);
    k_colfin<<<dim3(4), dim3(256), 0, stream>>>(cpm, cps, colred);
    k_ssum<<<dim3(TT - 1), dim3(256), 0, stream>>>(alpha, beta, ar, en, mkey, sbuf);
    k_fin<<<dim3(258), dim3(256), 0, stream>>>(mkey, sbuf, W, ar, en, rowred, colred, out);
}

// Round 8
// 573.786 us; speedup vs baseline: 5.4000x; 1.0446x over previous
//
#include <hip/hip_runtime.h>
#include <math.h>

#define AA 256
#define EE 256
#define CC (AA + EE + AA*EE)   // 66048
#define TT 1024
#define VV 1024
#define NSTRIP 16
#define NCHUNK 34              // 34*32 = 1088 steps
#define NEGBIG (-3.0e38f)      // finite stand-in for -inf in outputs
#define INVLN2 1.44269504088896340736f
#define LN2F   0.69314718055994530942f
#define SENT   0x7FC00001u     // NaN-payload sentinel for bnd
#define NINF   (-__builtin_inff())

// order-preserving float->uint key for atomicMax
__device__ __forceinline__ unsigned fkey(float f) {
    unsigned u = __float_as_uint(f);
    return (u & 0x80000000u) ? ~u : (u | 0x80000000u);
}
__device__ __forceinline__ float fdec(unsigned k) {
    return __uint_as_float((k & 0x80000000u) ? (k & 0x7FFFFFFFu) : ~k);
}
#define KEY_NEGINF 0x007FFFFFu   // fkey(-inf)

__device__ __forceinline__ float safe_out(float v) {
    if (!(v > NEGBIG)) return NEGBIG;   // catches -inf, NaN
    return v;
}

// ---------------- init: bins + bnd sentinel + W2 = W/ln2 ----------------
__global__ void k_init(const float* __restrict__ W, float* __restrict__ W2,
                       unsigned* __restrict__ mkey, float* __restrict__ sbuf,
                       unsigned* __restrict__ bndu) {
    int i = blockIdx.x * 256 + threadIdx.x;
    if (i < CC) { mkey[i] = 0u; sbuf[i] = 0.0f; W2[i] = W[i] * INVLN2; }
    if (i < 32 * 1024) bndu[i] = SENT;
}

// ---------------- pipelined strip DP: 32 blocks x 1 wave, log2 domain ----------------
// Blocks 0..15 forward (alpha), 16..31 backward (beta, mirrored). Lane = row rr=64b+tid,
// step d: col jk=d-tid. Lane dep via DPP wave_shr1 (lane0 takes boundary via DPP old).
// Substitution weights in LDS [e][row] (64KB), conflict-free. Handoff: per-chunk
// coalesced sc0sc1 publish (LDS-collected), poll at chunk start so the poll's
// vmcnt(0) never drains a young fabric store.
__global__ __launch_bounds__(64)
void k_dp_strip(const float* __restrict__ W2, const int* __restrict__ ar,
                const int* __restrict__ en,
                float* __restrict__ alpha, float* __restrict__ beta,
                float* __restrict__ bnd) {
    __shared__ float ws_lds[256 * 64];          // [e][row], 64KB
    __shared__ float wi_s[64 + 1088 + 16];
    __shared__ int   en_s[64 + 1088 + 16];
    __shared__ float seed_s[1024];
    __shared__ float pub[2][32];                // bottom-row collect, double buffer
    const int tid = threadIdx.x;
    const int dirb = blockIdx.x;                // 0..31
    const int dir = dirb >> 4, b = dirb & 15;
    const bool fwd = (dir == 0);
    const bool seed = (b == 0);
    const int rr = (b << 6) + tid;

    for (int x = tid; x < 64 + 1088 + 16; x += 64) {
        int col = x - 64;
        bool valid = (col >= 1 && col <= 1023);
        int e = valid ? en[fwd ? col : 1024 - col] : 0;
        en_s[x] = e;
        wi_s[x] = valid ? W2[AA + e] : 0.0f;
    }

    const int r_src = (rr >= 1) ? (fwd ? rr : (1024 - rr)) : 0;
    const float mywd2 = (rr >= 1) ? W2[ar[r_src]] : 0.0f;
    // stage this lane's substitution row into LDS [e][tid]
    {
        const float* wrow = W2 + AA + EE + ((rr >= 1) ? (ar[r_src] << 8) : 0);
        #pragma unroll 8
        for (int i = 0; i < 64; ++i) {
            float4 w = *(const float4*)(wrow + (i << 2));
            ws_lds[((i << 2) + 0) * 64 + tid] = w.x;
            ws_lds[((i << 2) + 1) * 64 + tid] = w.y;
            ws_lds[((i << 2) + 2) * 64 + tid] = w.z;
            ws_lds[((i << 2) + 3) * 64 + tid] = w.w;
        }
    }

    if (seed) {   // seed_s[x] = sum_{c=1..x} wi_s[64+c]
        float loc[16]; float s = 0.0f;
        #pragma unroll
        for (int i = 0; i < 16; ++i) {
            int x = (tid << 4) + i;
            float w = (x >= 1) ? wi_s[64 + x] : 0.0f;
            s += w; loc[i] = s;
        }
        float cum = s;
        for (int off = 1; off < 64; off <<= 1) {
            float tt = __shfl_up(cum, off);
            if (tid >= off) cum += tt;
        }
        float excl = cum - s;
        #pragma unroll
        for (int i = 0; i < 16; ++i) seed_s[(tid << 4) + i] = excl + loc[i];
    }
    __syncthreads();

    const int outrow = fwd ? (rr << 10) : ((1023 - rr) << 10);
    float* __restrict__ obase = fwd ? alpha : beta;
    float* __restrict__ bnd_me = bnd + (size_t)dirb * 1024;
    const float* __restrict__ bnd_prev = bnd + (size_t)(dirb - 1) * 1024;
    const bool seedlane = seed && (tid == 0);
    const int t3 = (tid + 3) & 3;               // store when (k&3)==t3

    float vm1 = NINF, upprev = NINF;
    float h0 = NINF, h1 = NINF, h2 = NINF;
    float wsv[8], wiv[8]; int env[8];
    #pragma unroll
    for (int s = 0; s < 8; ++s) env[s] = en_s[64 - tid + s];
    #pragma unroll
    for (int s = 0; s < 4; ++s) wiv[s] = wi_s[64 - tid + s];
    #pragma unroll
    for (int s = 0; s < 4; ++s) wsv[s] = ws_lds[(env[s] << 6) + tid];

    float bvals = NINF;

    for (int c = 0; c < NCHUNK; ++c) {
        const int dbase = c << 5;
        // ---- poll at chunk start (drains only old/fast stores) ----
        if (c <= 31) {
            if (seed) {
                bvals = seed_s[dbase + (tid & 31)];
            } else {
                const float* src = bnd_prev + dbase + (tid & 31);
                unsigned x;
                for (;;) {
                    asm volatile("global_load_dword %0, %1, off sc0 sc1\n\t"
                                 "s_waitcnt vmcnt(0)"
                                 : "=v"(x) : "v"(src) : "memory");
                    if (__ballot(x != SENT) == ~0ull) break;
                    __builtin_amdgcn_s_sleep(1);
                }
                bvals = __uint_as_float(x);
            }
        }
        #pragma unroll
        for (int k = 0; k < 32; ++k) {
            const int d = dbase + k;
            const int jk = d - tid;
            float bc = __int_as_float(__builtin_amdgcn_readlane(__float_as_int(bvals), k));
            float up1 = __int_as_float(__builtin_amdgcn_update_dpp(
                __float_as_int(bc), __float_as_int(vm1), 0x138 /*WAVE_SHR1*/, 0xF, 0xF, false));
            float del = mywd2 + up1;
            float sub = wsv[k & 7] + upprev;        // -inf guards fall out naturally
            float ins = vm1 + wiv[k & 7];
            float m3 = fmaxf(fmaxf(del, sub), ins);
            float me = __builtin_amdgcn_fmed3f(del, sub, ins);
            float mn = fminf(fminf(del, sub), ins);
            float v = m3 + __log2f(1.0f + exp2f(me - m3) + exp2f(mn - m3));
            const bool act = ((unsigned)jk < 1024u);
            v = act ? v : NINF;
            v = seedlane ? (act ? bc : NINF) : v;

            // software pipelines (LDS only, off critical path)
            wiv[(k + 4) & 7] = wi_s[64 - tid + d + 4];
            env[(k + 8) & 7] = en_s[64 - tid + d + 8];
            wsv[(k + 4) & 7] = ws_lds[(env[(k + 4) & 7] << 6) + tid];

            // bottom-row collect (LDS, cheap); col f=d-63 -> pub[(f>>5)&1][f&31]
            if (tid == 63 && act)
                pub[((d - 63) >> 5) & 1][(d - 63) & 31] = v;

            // row-major output: own row, float4 per 4 own-steps
            if (((k & 3) == t3) && act && jk >= 3) {
                float4 o = fwd ? make_float4(h2, h1, h0, v) : make_float4(v, h0, h1, h2);
                *(float4*)(obase + outrow + (fwd ? (jk - 3) : (1023 - jk))) = o;
            }
            h2 = h1; h1 = h0; h0 = v;
            upprev = up1; vm1 = v;
        }
        // ---- publish chunk c-2: one coalesced sc0sc1 store by lanes 0..31 ----
        if (b < NSTRIP - 1 && c >= 2) {
            float pv = pub[c & 1][tid & 31];      // (c-2)&1 == c&1
            if (tid < 32) {
                const float* dst = bnd_me + ((c - 2) << 5) + tid;
                asm volatile("global_store_dword %0, %1, off sc0 sc1"
                             :: "v"(dst), "v"(__float_as_uint(pv)) : "memory");
            }
        }
    }
}

// ---------------- block reduce helpers (256 threads = 4 waves) ----------------
__device__ __forceinline__ float blk_max(float v, float* sm) {
    for (int off = 32; off > 0; off >>= 1) v = fmaxf(v, __shfl_xor(v, off));
    if ((threadIdx.x & 63) == 0) sm[threadIdx.x >> 6] = v;
    __syncthreads();
    float r = fmaxf(fmaxf(sm[0], sm[1]), fmaxf(sm[2], sm[3]));
    __syncthreads();
    return r;
}
__device__ __forceinline__ float blk_sum(float v, float* sm) {
    for (int off = 32; off > 0; off >>= 1) v += __shfl_xor(v, off);
    if ((threadIdx.x & 63) == 0) sm[threadIdx.x >> 6] = v;
    __syncthreads();
    float r = sm[0] + sm[1] + sm[2] + sm[3];
    __syncthreads();
    return r;
}

// ---------------- fused: rowred[t] (delete LSE) + substitution atomicMax ----------------
__global__ __launch_bounds__(256)
void k_red1(const float* __restrict__ alpha, const float* __restrict__ beta,
            const int* __restrict__ ar, const int* __restrict__ en,
            float* __restrict__ rowred, unsigned* __restrict__ mkey) {
    __shared__ float sm[4];
    int t = 1 + blockIdx.x;
    int tid = threadIdx.x;
    int base = AA + EE + (ar[t] << 8);
    float v[4]; float m = NINF;
    #pragma unroll
    for (int i = 0; i < 4; ++i) {
        int j = tid + (i << 8);
        float b_ = beta[(size_t)t * VV + j];
        v[i] = alpha[(size_t)(t - 1) * VV + j] + b_;
        m = fmaxf(m, v[i]);
        if (j >= 1) {
            float vs = alpha[(size_t)(t - 1) * VV + (j - 1)] + b_;
            atomicMax(&mkey[base + en[j]], fkey(vs));
        }
    }
    m = blk_max(m, sm);
    float s = 0.0f;
    #pragma unroll
    for (int i = 0; i < 4; ++i) s += exp2f(v[i] - m);
    s = blk_sum(s, sm);
    if (tid == 0) rowred[t] = m + __log2f(s);
}

// ---------------- insert col reduction, stage 1: partials over 128-row bands ----------------
__global__ __launch_bounds__(256)
void k_colpart(const float* __restrict__ alpha, const float* __restrict__ beta,
               float* __restrict__ cpm, float* __restrict__ cps) {
    __shared__ float smm[4][64], sms[4][64];
    int c = threadIdx.x & 63;
    int g = threadIdx.x >> 6;
    int j = (blockIdx.x << 6) + c;
    int t0 = blockIdx.y << 7;
    float m = NINF, s = 0.0f;
    if (j >= 1) {
        for (int t = t0 + g; t < t0 + 128; t += 4) {
            float v = alpha[(size_t)t * 1024 + (j - 1)] + beta[(size_t)t * 1024 + j];
            if (v <= m) s += exp2f(v - m);
            else { s = s * exp2f(m - v) + 1.0f; m = v; }
        }
    }
    smm[g][c] = m; sms[g][c] = s;
    __syncthreads();
    if (g == 0) {
        float M = m, S = s;
        for (int k = 1; k < 4; ++k) {
            float mk = smm[k][c], sk = sms[k][c];
            if (mk <= M) S += sk * exp2f(mk - M);
            else { S = S * exp2f(M - mk) + sk; M = mk; }
        }
        cpm[(size_t)blockIdx.y * 1024 + j] = M;
        cps[(size_t)blockIdx.y * 1024 + j] = S;
    }
}
// stage 2: merge 8 bands
__global__ void k_colfin(const float* __restrict__ cpm, const float* __restrict__ cps,
                         float* __restrict__ colred) {
    int j = blockIdx.x * 256 + threadIdx.x;
    float M = NINF, S = 0.0f;
    for (int k = 0; k < 8; ++k) {
        float mk = cpm[(size_t)k * 1024 + j], sk = cps[(size_t)k * 1024 + j];
        if (mk <= M) S += sk * exp2f(mk - M);
        else { S = S * exp2f(M - mk) + sk; M = mk; }
    }
    colred[j] = (j >= 1) ? (M + __log2f(S)) : NINF;
}

// ---------------- substitution bins: sum pass (needs mkey) ----------------
__global__ void k_ssum(const float* __restrict__ alpha, const float* __restrict__ beta,
                       const int* __restrict__ ar, const int* __restrict__ en,
                       const unsigned* __restrict__ mkey, float* __restrict__ sbuf) {
    int t = 1 + blockIdx.x;
    int base = AA + EE + (ar[t] << 8);
    for (int j = 1 + threadIdx.x; j <= VV - 1; j += 256) {
        float v = alpha[(size_t)(t - 1) * VV + (j - 1)] + beta[(size_t)t * VV + j];
        int b = base + en[j];
        atomicAdd(&sbuf[b], exp2f(v - fdec(mkey[b])));
    }
}

// ---------------- finalize: sub bins (blocks 0..255), dbins (256), ibins (257) ----------------
__global__ __launch_bounds__(256)
void k_fin(const unsigned* __restrict__ mkey, const float* __restrict__ sbuf,
           const float* __restrict__ W, const int* __restrict__ ar,
           const int* __restrict__ en, const float* __restrict__ rowred,
           const float* __restrict__ colred, float* __restrict__ out) {
    __shared__ float fv[1024];
    __shared__ int   iv[1024];
    int blk = blockIdx.x;
    int tid = threadIdx.x;
    if (blk < 256) {
        int id = AA + EE + blk * 256 + tid;
        unsigned key = mkey[id];
        float v = (key > KEY_NEGINF) ? (W[id] + LN2F * (fdec(key) + __log2f(sbuf[id]))) : NEGBIG;
        out[id] = safe_out(v);
        return;
    }
    const bool isd = (blk == 256);
    for (int x = tid; x < 1024; x += 256) {
        fv[x] = isd ? rowred[x] : colred[x];
        iv[x] = isd ? ar[x] : en[x];
    }
    __syncthreads();
    float m = NINF, s = 0.0f;
    for (int t = 1; t < 1024; ++t) {
        if (iv[t] == tid) {
            float v = fv[t];
            if (v <= m) s += exp2f(v - m);
            else { s = s * exp2f(m - v) + 1.0f; m = v; }
        }
    }
    int oid = isd ? tid : (AA + tid);
    float v = (m == NINF) ? NEGBIG : (W[oid] + LN2F * (m + __log2f(s)));
    out[oid] = safe_out(v);
}

extern "C" void kernel_launch(void* const* d_in, const int* in_sizes, int n_in,
                              void* d_out, int out_size, void* d_ws, size_t ws_size,
                              hipStream_t stream) {
    const float* W  = (const float*)d_in[0];
    const int*   ar = (const int*)d_in[1];
    const int*   en = (const int*)d_in[2];
    float* out = (float*)d_out;

    char* p = (char*)d_ws;
    float* W2      = (float*)p; p += (size_t)CC * 4;
    float* alpha   = (float*)p; p += (size_t)TT * VV * 4;
    float* beta    = (float*)p; p += (size_t)TT * VV * 4;
    float* bnd     = (float*)p; p += (size_t)32 * 1024 * 4;
    float* rowred  = (float*)p; p += TT * 4;
    float* colred  = (float*)p; p += VV * 4;
    float* cpm     = (float*)p; p += (size_t)8 * 1024 * 4;
    float* cps     = (float*)p; p += (size_t)8 * 1024 * 4;
    float* sbuf    = (float*)p; p += (size_t)CC * 4;
    unsigned* mkey = (unsigned*)p; p += (size_t)CC * 4;

    k_init<<<dim3((CC + 255) / 256), dim3(256), 0, stream>>>(W, W2, mkey, sbuf, (unsigned*)bnd);
    k_dp_strip<<<dim3(32), dim3(64), 0, stream>>>(W2, ar, en, alpha, beta, bnd);
    k_red1<<<dim3(TT - 1), dim3(256), 0, stream>>>(alpha, beta, ar, en, rowred, mkey);
    k_colpart<<<dim3(16, 8), dim3(256), 0, stream>>>(alpha, beta, cpm, cps);
    k_colfin<<<dim3(4), dim3(256), 0, stream>>>(cpm, cps, colred);
    k_ssum<<<dim3(TT - 1), dim3(256), 0, stream>>>(alpha, beta, ar, en, mkey, sbuf);
    k_fin<<<dim3(258), dim3(256), 0, stream>>>(mkey, sbuf, W, ar, en, rowred, colred, out);
}

// Round 12
// 470.610 us; speedup vs baseline: 6.5838x; 1.2192x over previous
//
#include <hip/hip_runtime.h>

#define AA 256
#define EE 256
#define CC (AA + EE + AA*EE)   // 66048
#define TT 1024
#define VV 1024
#define NSTRIP 16
#define NCHUNKS 36             // 36 chunks x 16 supersteps = 576 supersteps
#define NEGBIG (-3.0e38f)      // finite stand-in for -inf in outputs
#define INVLN2 1.44269504088896340736f
#define LN2F   0.69314718055994530942f
#define SENT   0x7FC00001u     // NaN-payload sentinel for bnd
#define NINF   (-__builtin_inff())

#define E2(x) __builtin_amdgcn_exp2f(x)  // native v_exp_f32: 2^x
#define L2(x) __builtin_amdgcn_logf(x)   // native v_log_f32: log2(x)

// order-preserving float->uint key for atomicMax
__device__ __forceinline__ unsigned fkey(float f) {
    unsigned u = __float_as_uint(f);
    return (u & 0x80000000u) ? ~u : (u | 0x80000000u);
}
__device__ __forceinline__ float fdec(unsigned k) {
    return __uint_as_float((k & 0x80000000u) ? (k & 0x7FFFFFFFu) : ~k);
}
#define KEY_NEGINF 0x007FFFFFu   // fkey(-inf)

__device__ __forceinline__ float safe_out(float v) {
    if (!(v > NEGBIG)) return NEGBIG;   // catches -inf, NaN
    return v;
}

__device__ __forceinline__ float lse3(float x, float y, float z) {
    float m3 = fmaxf(fmaxf(x, y), z);
    float me = __builtin_amdgcn_fmed3f(x, y, z);
    float mn = fminf(fminf(x, y), z);
    return m3 + L2(1.0f + E2(me - m3) + E2(mn - m3));
}

// ---------------- init: bins + bnd sentinel + W2 = W/ln2 ----------------
__global__ void k_init(const float* __restrict__ W, float* __restrict__ W2,
                       unsigned* __restrict__ mkey, float* __restrict__ sbuf,
                       unsigned* __restrict__ bndu) {
    int i = blockIdx.x * 256 + threadIdx.x;
    if (i < CC) { mkey[i] = 0u; sbuf[i] = 0.0f; W2[i] = W[i] * INVLN2; }
    if (i < 32 * 1024) bndu[i] = SENT;
}

// ---------------- pipelined strip DP: 32 blocks x 1 wave, 2 cells/lane/superstep ----------------
// Blocks 0..15 forward (alpha), 16..31 backward (beta, mirrored). Lane r = row rr=64b+r.
// Superstep S: lane r computes cols a=2(S-r), b=a+1. Lane r-1's previous superstep
// produced exactly V(row-1, a), V(row-1, b) -> 2 DPP shifts feed del/sub of both cells.
// ws in LDS [e][row] (conflict-free); native exp2/log2; no global loads in loop.
__global__ __launch_bounds__(64)
void k_dp_strip(const float* __restrict__ W2, const int* __restrict__ ar,
                const int* __restrict__ en,
                float* __restrict__ alpha, float* __restrict__ beta,
                float* __restrict__ bnd) {
    __shared__ float ws_lds[256 * 64];          // [e][row], 64KB
    __shared__ float wi_s[1312];                // col = idx-128, valid 1..1023
    __shared__ int   en_s[1312];
    __shared__ float seed_s[1024];
    __shared__ float pub[2][32];                // bottom-row collect by column
    const int tid = threadIdx.x;
    const int dirb = blockIdx.x;                // 0..31
    const int dir = dirb >> 4, b = dirb & 15;
    const bool fwd = (dir == 0);
    const bool seedstrip = (b == 0);
    const int rr = (b << 6) + tid;

    for (int x = tid; x < 1312; x += 64) {
        int col = x - 128;
        bool valid = (col >= 1 && col <= 1023);
        int e = valid ? en[fwd ? col : 1024 - col] : 0;
        en_s[x] = e;
        wi_s[x] = valid ? W2[AA + e] : 0.0f;
    }

    const int r_src = (rr >= 1) ? (fwd ? rr : (1024 - rr)) : 0;
    const float mywd2 = (rr >= 1) ? W2[ar[r_src]] : 0.0f;
    {   // stage this lane's substitution row into LDS [e][tid] (bank = tid%32, conflict-free)
        const float* wrow = W2 + AA + EE + ((rr >= 1) ? (ar[r_src] << 8) : 0);
        #pragma unroll 8
        for (int i = 0; i < 64; ++i) {
            float4 w = *(const float4*)(wrow + (i << 2));
            ws_lds[((i << 2) + 0) * 64 + tid] = w.x;
            ws_lds[((i << 2) + 1) * 64 + tid] = w.y;
            ws_lds[((i << 2) + 2) * 64 + tid] = w.z;
            ws_lds[((i << 2) + 3) * 64 + tid] = w.w;
        }
    }

    if (seedstrip) {   // seed_s[x] = sum_{c=1..x} wi_s[128+c]
        float loc[16]; float s = 0.0f;
        #pragma unroll
        for (int i = 0; i < 16; ++i) {
            int x = (tid << 4) + i;
            float w = (x >= 1) ? wi_s[128 + x] : 0.0f;
            s += w; loc[i] = s;
        }
        float cum = s;
        for (int off = 1; off < 64; off <<= 1) {
            float tt = __shfl_up(cum, off);
            if (tid >= off) cum += tt;
        }
        float excl = cum - s;
        #pragma unroll
        for (int i = 0; i < 16; ++i) seed_s[(tid << 4) + i] = excl + loc[i];
    }
    __syncthreads();

    const int outrow = fwd ? (rr << 10) : ((1023 - rr) << 10);
    float* __restrict__ obase = fwd ? alpha : beta;
    float* __restrict__ bnd_me = bnd + (size_t)dirb * 1024;
    const float* __restrict__ bnd_prev = bnd + (size_t)(dirb - 1) * 1024;
    const bool seedlane = seedstrip && (tid == 0);

    float vA = NINF, vB = NINF, upBp = NINF;
    int2   env[8];   // en pairs, prefetched 8 supersteps ahead
    float2 wiv[4];   // wi pairs, 4 ahead
    float2 wsv[4];   // ws pairs, 4 ahead
    #pragma unroll
    for (int s = 0; s < 8; ++s) env[s] = *(const int2*)&en_s[128 + 2 * s - 2 * tid];
    #pragma unroll
    for (int s = 0; s < 4; ++s) wiv[s] = *(const float2*)&wi_s[128 + 2 * s - 2 * tid];
    #pragma unroll
    for (int s = 0; s < 4; ++s)
        wsv[s] = make_float2(ws_lds[(env[s].x << 6) + tid], ws_lds[(env[s].y << 6) + tid]);

    float bvals = NINF;

    for (int c = 0; c < NCHUNKS; ++c) {
        // ---- fetch boundary cols 32c..32c+31 (consumer) ----
        if (c <= 31) {
            if (seedstrip) {
                bvals = seed_s[(c << 5) + (tid & 31)];
            } else {
                const float* src = bnd_prev + (c << 5) + (tid & 31);
                unsigned x;
                for (;;) {
                    asm volatile("global_load_dword %0, %1, off sc0 sc1\n\t"
                                 "s_waitcnt vmcnt(0)"
                                 : "=v"(x) : "v"(src) : "memory");
                    if (__ballot(x != SENT) == ~0ull) break;
                    __builtin_amdgcn_s_sleep(1);
                }
                bvals = __uint_as_float(x);
            }
        }
        #pragma unroll
        for (int k = 0; k < 16; ++k) {
            const int S = (c << 4) + k;
            const int sd = S - tid;                  // a = 2*sd
            const bool act = ((unsigned)sd < 512u);
            float bca = __int_as_float(__builtin_amdgcn_readlane(__float_as_int(bvals), 2 * k));
            float bcb = __int_as_float(__builtin_amdgcn_readlane(__float_as_int(bvals), 2 * k + 1));
            float upA = __int_as_float(__builtin_amdgcn_update_dpp(
                __float_as_int(bca), __float_as_int(vA), 0x138, 0xF, 0xF, false));
            float upB = __int_as_float(__builtin_amdgcn_update_dpp(
                __float_as_int(bcb), __float_as_int(vB), 0x138, 0xF, 0xF, false));
            float2 wsp = wsv[k & 3];
            float2 wip = wiv[k & 3];
            // software pipelines (issue early; LDS only)
            int2   ep  = *(const int2*)&en_s[128 + 2 * S + 16 - 2 * tid];    // for S+8
            float2 win = *(const float2*)&wi_s[128 + 2 * S + 8 - 2 * tid];   // for S+4
            int2   ec  = env[(k + 4) & 7];                                   // en for S+4
            float  wsx = ws_lds[(ec.x << 6) + tid];
            float  wsy = ws_lds[(ec.y << 6) + tid];

            // cell a
            float dela = mywd2 + upA;                // wd + V(r-1, a)
            float suba = wsp.x + upBp;               // ws[a] + V(r-1, a-1)
            float insa = wip.x + vB;                 // wi[a] + V(r, a-1)
            float VA = lse3(dela, suba, insa);
            VA = seedlane ? bca : VA;
            VA = act ? VA : NINF;
            // cell b = a+1
            float delb = mywd2 + upB;                // wd + V(r-1, b)
            float subb = wsp.y + upA;                // ws[b] + V(r-1, a)
            float insb = wip.y + VA;                 // wi[b] + V(r, a)
            float VB = lse3(delb, subb, insb);
            VB = seedlane ? bcb : VB;
            VB = act ? VB : NINF;

            env[(k + 8) & 7] = ep;
            wiv[(k + 4) & 3] = win;
            wsv[(k + 4) & 3] = make_float2(wsx, wsy);

            if (act) {
                const int a = 2 * sd;
                if (tid == 63)                        // bottom-row collect by column
                    *(float2*)&pub[(a >> 5) & 1][a & 31] = make_float2(VA, VB);
                if (fwd) *(float2*)(obase + outrow + a) = make_float2(VA, VB);
                else     *(float2*)(obase + outrow + (1022 - a)) = make_float2(VB, VA);
            }
            upBp = upB; vA = VA; vB = VB;
        }
        // ---- publish col-chunk q=c-4 (complete as of superstep 16c+15) ----
        if (b < NSTRIP - 1 && c >= 4) {
            const int q = c - 4;
            float pv = pub[q & 1][tid & 31];
            if (tid < 32) {
                const float* dst = bnd_me + (q << 5) + tid;
                asm volatile("global_store_dword %0, %1, off sc0 sc1"
                             :: "v"(dst), "v"(__float_as_uint(pv)) : "memory");
            }
        }
    }
}

// ---------------- block reduce helpers (256 threads = 4 waves) ----------------
__device__ __forceinline__ float blk_max(float v, float* sm) {
    for (int off = 32; off > 0; off >>= 1) v = fmaxf(v, __shfl_xor(v, off));
    if ((threadIdx.x & 63) == 0) sm[threadIdx.x >> 6] = v;
    __syncthreads();
    float r = fmaxf(fmaxf(sm[0], sm[1]), fmaxf(sm[2], sm[3]));
    __syncthreads();
    return r;
}
__device__ __forceinline__ float blk_sum(float v, float* sm) {
    for (int off = 32; off > 0; off >>= 1) v += __shfl_xor(v, off);
    if ((threadIdx.x & 63) == 0) sm[threadIdx.x >> 6] = v;
    __syncthreads();
    float r = sm[0] + sm[1] + sm[2] + sm[3];
    __syncthreads();
    return r;
}

// ---------------- fused: rowred[t] (delete LSE) + substitution atomicMax ----------------
__global__ __launch_bounds__(256)
void k_red1(const float* __restrict__ alpha, const float* __restrict__ beta,
            const int* __restrict__ ar, const int* __restrict__ en,
            float* __restrict__ rowred, unsigned* __restrict__ mkey) {
    __shared__ float sm[4];
    int t = 1 + blockIdx.x;
    int tid = threadIdx.x;
    int base = AA + EE + (ar[t] << 8);
    float v[4]; float m = NINF;
    #pragma unroll
    for (int i = 0; i < 4; ++i) {
        int j = tid + (i << 8);
        float b_ = beta[(size_t)t * VV + j];
        v[i] = alpha[(size_t)(t - 1) * VV + j] + b_;
        m = fmaxf(m, v[i]);
        if (j >= 1) {
            float vs = alpha[(size_t)(t - 1) * VV + (j - 1)] + b_;
            atomicMax(&mkey[base + en[j]], fkey(vs));
        }
    }
    m = blk_max(m, sm);
    float s = 0.0f;
    #pragma unroll
    for (int i = 0; i < 4; ++i) s += E2(v[i] - m);
    s = blk_sum(s, sm);
    if (tid == 0) rowred[t] = m + L2(s);
}

// ---------------- insert col reduction, stage 1: partials over 128-row bands ----------------
__global__ __launch_bounds__(256)
void k_colpart(const float* __restrict__ alpha, const float* __restrict__ beta,
               float* __restrict__ cpm, float* __restrict__ cps) {
    __shared__ float smm[4][64], sms[4][64];
    int c = threadIdx.x & 63;
    int g = threadIdx.x >> 6;
    int j = (blockIdx.x << 6) + c;
    int t0 = blockIdx.y << 7;
    float m = NINF, s = 0.0f;
    if (j >= 1) {
        for (int t = t0 + g; t < t0 + 128; t += 4) {
            float v = alpha[(size_t)t * 1024 + (j - 1)] + beta[(size_t)t * 1024 + j];
            if (v <= m) s += E2(v - m);
            else { s = s * E2(m - v) + 1.0f; m = v; }
        }
    }
    smm[g][c] = m; sms[g][c] = s;
    __syncthreads();
    if (g == 0) {
        float M = m, S = s;
        for (int k = 1; k < 4; ++k) {
            float mk = smm[k][c], sk = sms[k][c];
            if (mk <= M) S += sk * E2(mk - M);
            else { S = S * E2(M - mk) + sk; M = mk; }
        }
        cpm[(size_t)blockIdx.y * 1024 + j] = M;
        cps[(size_t)blockIdx.y * 1024 + j] = S;
    }
}
// stage 2: merge 8 bands
__global__ void k_colfin(const float* __restrict__ cpm, const float* __restrict__ cps,
                         float* __restrict__ colred) {
    int j = blockIdx.x * 256 + threadIdx.x;
    float M = NINF, S = 0.0f;
    for (int k = 0; k < 8; ++k) {
        float mk = cpm[(size_t)k * 1024 + j], sk = cps[(size_t)k * 1024 + j];
        if (mk <= M) S += sk * E2(mk - M);
        else { S = S * E2(M - mk) + sk; M = mk; }
    }
    colred[j] = (j >= 1) ? (M + L2(S)) : NINF;
}

// ---------------- substitution bins: sum pass (needs mkey) ----------------
__global__ void k_ssum(const float* __restrict__ alpha, const float* __restrict__ beta,
                       const int* __restrict__ ar, const int* __restrict__ en,
                       const unsigned* __restrict__ mkey, float* __restrict__ sbuf) {
    int t = 1 + blockIdx.x;
    int base = AA + EE + (ar[t] << 8);
    for (int j = 1 + threadIdx.x; j <= VV - 1; j += 256) {
        float v = alpha[(size_t)(t - 1) * VV + (j - 1)] + beta[(size_t)t * VV + j];
        int b = base + en[j];
        atomicAdd(&sbuf[b], E2(v - fdec(mkey[b])));
    }
}

// ---------------- finalize: sub bins (blocks 0..255), dbins (256), ibins (257) ----------------
__global__ __launch_bounds__(256)
void k_fin(const unsigned* __restrict__ mkey, const float* __restrict__ sbuf,
           const float* __restrict__ W, const int* __restrict__ ar,
           const int* __restrict__ en, const float* __restrict__ rowred,
           const float* __restrict__ colred, float* __restrict__ out) {
    __shared__ float fv[1024];
    __shared__ int   iv[1024];
    int blk = blockIdx.x;
    int tid = threadIdx.x;
    if (blk < 256) {
        int id = AA + EE + blk * 256 + tid;
        unsigned key = mkey[id];
        float v = (key > KEY_NEGINF) ? (W[id] + LN2F * (fdec(key) + L2(sbuf[id]))) : NEGBIG;
        out[id] = safe_out(v);
        return;
    }
    const bool isd = (blk == 256);
    for (int x = tid; x < 1024; x += 256) {
        fv[x] = isd ? rowred[x] : colred[x];
        iv[x] = isd ? ar[x] : en[x];
    }
    __syncthreads();
    float m = NINF, s = 0.0f;
    for (int t = 1; t < 1024; ++t) {
        if (iv[t] == tid) {
            float v = fv[t];
            if (v <= m) s += E2(v - m);
            else { s = s * E2(m - v) + 1.0f; m = v; }
        }
    }
    int oid = isd ? tid : (AA + tid);
    float v = (m == NINF) ? NEGBIG : (W[oid] + LN2F * (m + L2(s)));
    out[oid] = safe_out(v);
}

extern "C" void kernel_launch(void* const* d_in, const int* in_sizes, int n_in,
                              void* d_out, int out_size, void* d_ws, size_t ws_size,
                              hipStream_t stream) {
    const float* W  = (const float*)d_in[0];
    const int*   ar = (const int*)d_in[1];
    const int*   en = (const int*)d_in[2];
    float* out = (float*)d_out;

    char* p = (char*)d_ws;
    float* W2      = (float*)p; p += (size_t)CC * 4;
    float* alpha   = (float*)p; p += (size_t)TT * VV * 4;
    float* beta    = (float*)p; p += (size_t)TT * VV * 4;
    float* bnd     = (float*)p; p += (size_t)32 * 1024 * 4;
    float* rowred  = (float*)p; p += TT * 4;
    float* colred  = (float*)p; p += VV * 4;
    float* cpm     = (float*)p; p += (size_t)8 * 1024 * 4;
    float* cps     = (float*)p; p += (size_t)8 * 1024 * 4;
    float* sbuf    = (float*)p; p += (size_t)CC * 4;
    unsigned* mkey = (unsigned*)p; p += (size_t)CC * 4;

    k_init<<<dim3((CC + 255) / 256), dim3(256), 0, stream>>>(W, W2, mkey, sbuf, (unsigned*)bnd);
    k_dp_strip<<<dim3(32), dim3(64), 0, stream>>>(W2, ar, en, alpha, beta, bnd);
    k_red1<<<dim3(TT - 1), dim3(256), 0, stream>>>(alpha, beta, ar, en, rowred, mkey);
    k_colpart<<<dim3(16, 8), dim3(256), 0, stream>>>(alpha, beta, cpm, cps);
    k_colfin<<<dim3(4), dim3(256), 0, stream>>>(cpm, cps, colred);
    k_ssum<<<dim3(TT - 1), dim3(256), 0, stream>>>(alpha, beta, ar, en, mkey, sbuf);
    k_fin<<<dim3(258), dim3(256), 0, stream>>>(mkey, sbuf, W, ar, en, rowred, colred, out);
}